// Round 3
// baseline (399.918 us; speedup 1.0000x reference)
//
#include <hip/hip_runtime.h>
#include <hip/hip_bf16.h>

constexpr int Bn = 16, Cn = 24, Sn = 128, En = 256, Hn = 8, Pn = 32;
constexpr int NROWS = Bn * Cn * Sn;                  // 49152
constexpr size_t NBUF = (size_t)Bn * Cn * Sn * En;   // 12,582,912 elems
constexpr size_t WSLOT = (size_t)Cn * 256 * 256;     // 1,572,864

typedef __bf16 bf16_t;
typedef bf16_t bf16x8 __attribute__((ext_vector_type(8)));
typedef bf16_t bf16x4 __attribute__((ext_vector_type(4)));
typedef float f32x4 __attribute__((ext_vector_type(4)));

// global -> LDS direct 16B copy (dest = wave-uniform base + lane*16)
__device__ __forceinline__ void gl2lds16(const bf16_t* g, bf16_t* l) {
    typedef const __attribute__((address_space(1))) unsigned int* gp_t;
    typedef __attribute__((address_space(3))) unsigned int* lp_t;
    __builtin_amdgcn_global_load_lds((gp_t)(unsigned long long)g,
                                     (lp_t)(unsigned int)(unsigned long long)l,
                                     16, 0, 0);
}

// ---------------------------------------------------------------------------
// x fp32 -> bf16
// ---------------------------------------------------------------------------
__global__ __launch_bounds__(256) void conv_x_k(const float* __restrict__ x,
                                                bf16_t* __restrict__ xb) {
    const size_t i = ((size_t)blockIdx.x * 256 + threadIdx.x) * 4;
    const float4 v = *(const float4*)(x + i);
    bf16x4 o = {(bf16_t)v.x, (bf16_t)v.y, (bf16_t)v.z, (bf16_t)v.w};
    *(bf16x4*)(xb + i) = o;
}

// ---------------------------------------------------------------------------
// Wq_s copy-convert (source already e-contiguous): [h,c,p,e] -> [c][n=h*32+p][e]
// ---------------------------------------------------------------------------
__global__ __launch_bounds__(256) void conv_w_copy_k(const float* __restrict__ W,
                                                     bf16_t* __restrict__ out) {
    const int row = blockIdx.x * 4 + (threadIdx.x >> 6);   // c*256+n
    const int lane = threadIdx.x & 63;
    const int n = row & 255, c = row >> 8;
    const float* src = W + (size_t)c * (Pn * En) + (size_t)(n >> 5) * (Cn * Pn * En) +
                       (size_t)(n & 31) * En + lane * 4;
    const float4 v = *(const float4*)src;
    bf16x4 o = {(bf16_t)v.x, (bf16_t)v.y, (bf16_t)v.z, (bf16_t)v.w};
    *(bf16x4*)(out + (size_t)row * 256 + lane * 4) = o;
}

// ---------------------------------------------------------------------------
// Transpose-convert for the 7 e-strided weights -> canonical [slot][c][n][e].
// ---------------------------------------------------------------------------
struct TDesc { const float* W; int Sc, Snh, Se; };

__global__ __launch_bounds__(256) void conv_w_tr_k(
    TDesc d0, TDesc d1, TDesc d2, TDesc d3, TDesc d4, TDesc d5, TDesc d6,
    bf16_t* __restrict__ out)
{
    TDesc d;
    switch (blockIdx.z) {
        case 0: d = d0; break; case 1: d = d1; break; case 2: d = d2; break;
        case 3: d = d3; break; case 4: d = d4; break; case 5: d = d5; break;
        default: d = d6; break;
    }
    const int g = blockIdx.x & 7, et = blockIdx.x >> 3;
    const int c = blockIdx.y;

    __shared__ float tile[32][65];

    const int t = threadIdx.x;
    const float* base = d.W + (size_t)c * d.Sc + (size_t)g * d.Snh;

#pragma unroll
    for (int pass = 0; pass < 2; ++pass) {
        const int e_local = pass * 32 + (t >> 3);
        const int j4 = (t & 7) * 4;
        const float4 v = *(const float4*)(base + (size_t)(et * 64 + e_local) * d.Se + j4);
        tile[j4 + 0][e_local] = v.x;
        tile[j4 + 1][e_local] = v.y;
        tile[j4 + 2][e_local] = v.z;
        tile[j4 + 3][e_local] = v.w;
    }
    __syncthreads();

    const int j = t >> 3, e8 = (t & 7) * 8;
    bf16x8 o;
#pragma unroll
    for (int k = 0; k < 8; ++k) o[k] = (bf16_t)tile[j][e8 + k];
    *(bf16x8*)(out + (size_t)blockIdx.z * WSLOT +
               ((size_t)c * 256 + g * 32 + j) * 256 + et * 64 + e8) = o;
}

// small shared spatial k/v weights (tiny: 64 KB each)
__global__ __launch_bounds__(256) void conv_w_k(const float* __restrict__ W,
                                                bf16_t* __restrict__ Wb,
                                                int Sc, int Snh, int Snp, int Se) {
    const int n = blockIdx.x & 255, c = blockIdx.x >> 8;
    const int e = threadIdx.x;
    Wb[(size_t)blockIdx.x * 256 + e] =
        (bf16_t)W[(size_t)c * Sc + (size_t)(n >> 5) * Snh + (n & 31) * Snp + (size_t)e * Se];
}

// ---------------------------------------------------------------------------
// bf16 MFMA GEMM. Tile = 256x128 (M pairs two b's: rows 0-127 -> b=2bx,
// 128-255 -> b=2bx+1), BK=32, 4 waves stacked on M (wave = 64 rows x 128 cols,
// acc[4][8], 32 MFMA per K-step per wave). K-loop = counted-vmcnt pipeline
// (T3+T4): 3 LDS buffers, depth-2 prefetch, s_waitcnt vmcnt(12) steady state
// (6 load-insts/wave/stage), never 0 until tail.
// trans=0: output n-inner; trans=1: output m-inner (16B stores along m, Os==1).
// EPI: 0 / 1 (bias+relu) / 2 (bias)  (trans=0 path only)
// ---------------------------------------------------------------------------
struct GDesc { const bf16_t* W; bf16_t* O; int Aoff, Wc, Ob, Oc, Os, Onh, Onp, trans; };

template <int NP, int EPI>
__global__ __launch_bounds__(256, 2) void gemm_mfma(
    const bf16_t* __restrict__ A, int Ab, int Ac, int As,
    GDesc g0, GDesc g1, GDesc g2, const float* __restrict__ bias)
{
    const int bx = blockIdx.x, c = blockIdx.z;
    const int proj = (NP == 1) ? 0 : ((int)blockIdx.y >> 1);
    const int nt = (NP == 1) ? (int)blockIdx.y : ((int)blockIdx.y & 1);
    GDesc g = (proj == 0) ? g0 : (proj == 1) ? g1 : g2;

    // per buffer: A tile 256x32 at [0,8192), B tile 128x32 at [8192,12288)
    __shared__ bf16_t smem[3][12288];          // 72 KB
    bf16_t* Cs = &smem[0][0];                  // epilogue staging (aliased)

    const int tid = threadIdx.x, wv = tid >> 6, ln = tid & 63;
    const int wm = wv * 64;
    const int lr = ln & 15, hi = ln >> 4, lk = hi * 8;

    const bf16_t* Abase = A + g.Aoff + (size_t)(bx * 2) * Ab + (size_t)c * Ac;
    const bf16_t* Bbase = g.W + (size_t)c * g.Wc + (size_t)(nt * 128) * 256;

    // stage tile kt (256x32 A + 128x32 B, 24 KB) into buffer `buf`; 6 insts/wave
    auto stage = [&](int buf, int kt) {
        const int k0 = kt * 32;
#pragma unroll
        for (int ga = 0; ga < 4; ++ga) {
            const int ch = ga * 256 + wv * 64 + ln;      // 16B chunk id, [0,1024)
            const int row = ch >> 2, q = (ch & 3) * 8;
            gl2lds16(Abase + (size_t)(row >> 7) * Ab + (size_t)(row & 127) * As + k0 + q,
                     &smem[buf][ch * 8]);
        }
#pragma unroll
        for (int gb = 0; gb < 2; ++gb) {
            const int ch = gb * 256 + wv * 64 + ln;      // [0,512)
            const int row = ch >> 2, q = (ch & 3) * 8;
            gl2lds16(Bbase + (size_t)row * 256 + k0 + q, &smem[buf][8192 + ch * 8]);
        }
    };

    f32x4 acc[4][8] = {};

    stage(0, 0);               // 6 vm-insts/wave
    stage(1, 1);               // 12 outstanding

#pragma unroll
    for (int kt = 0; kt < 8; ++kt) {
        if (kt < 6) stage((kt + 2) % 3, kt + 2);
        // drain only tile kt's 6 loads; keep the younger 12 (or 6/0 at tail)
        if (kt < 6)       asm volatile("s_waitcnt vmcnt(12)" ::: "memory");
        else if (kt == 6) asm volatile("s_waitcnt vmcnt(6)" ::: "memory");
        else              asm volatile("s_waitcnt vmcnt(0)" ::: "memory");
        __builtin_amdgcn_s_barrier();              // buf kt%3 fully loaded
        __builtin_amdgcn_sched_barrier(0);

        const int cur = kt % 3;
        bf16x8 af[4];
#pragma unroll
        for (int i = 0; i < 4; ++i)
            af[i] = *(const bf16x8*)&smem[cur][(wm + i * 16 + lr) * 32 + lk];
        __builtin_amdgcn_s_setprio(1);
#pragma unroll
        for (int j = 0; j < 8; ++j) {
            bf16x8 bf = *(const bf16x8*)&smem[cur][8192 + (j * 16 + lr) * 32 + lk];
#pragma unroll
            for (int i = 0; i < 4; ++i)
                acc[i][j] = __builtin_amdgcn_mfma_f32_16x16x32_bf16(af[i], bf, acc[i][j], 0, 0, 0);
        }
        __builtin_amdgcn_s_setprio(0);

        __builtin_amdgcn_sched_barrier(0);
        __builtin_amdgcn_s_barrier();              // protect buf cur before rewrite
    }

    // ---- LDS-staged epilogue (Cs aliases smem; vmcnt drained at kt=7) ----
    // mfma C/D layout: n = j*16 + lr, m = wm + i*16 + hi*4 + r
#pragma unroll
    for (int pass = 0; pass < 2; ++pass) {
        if (!g.trans) {
            // pass covers m in [pass*128, pass*128+128)  (exactly b = bx*2+pass)
            if ((wv >> 1) == pass) {
#pragma unroll
                for (int i = 0; i < 4; ++i)
#pragma unroll
                    for (int j = 0; j < 8; ++j) {
                        const int n = nt * 128 + j * 16 + lr;
                        float bv = 0.f;
                        if (EPI) bv = bias[c * 256 + n];
#pragma unroll
                        for (int r = 0; r < 4; ++r) {
                            float v = acc[i][j][r];
                            if (EPI) { v += bv; if (EPI == 1) v = fmaxf(v, 0.f); }
                            Cs[((wv & 1) * 64 + i * 16 + hi * 4 + r) * 136 + j * 16 + lr] = (bf16_t)v;
                        }
                    }
            }
            __syncthreads();
#pragma unroll
            for (int it = 0; it < 4; ++it) {
                const int lrow = it * 32 + (tid >> 3);       // [0,128)
                const int n0 = (tid & 7) * 16;
                bf16x8 v0 = *(const bf16x8*)&Cs[lrow * 136 + n0];
                bf16x8 v1 = *(const bf16x8*)&Cs[lrow * 136 + n0 + 8];
                const int n = nt * 128 + n0;
                bf16_t* dst = g.O + (size_t)(bx * 2 + pass) * g.Ob + (size_t)c * g.Oc +
                              (size_t)lrow * g.Os + (size_t)(n >> 5) * g.Onh + (n & 31);
                *(bf16x8*)dst = v0;
                *(bf16x8*)(dst + 8) = v1;
            }
            __syncthreads();
        } else {
            // pass covers n-local in [pass*64, pass*64+64); all waves write
            // their m-quarter. Cs is [64][264] (n-local x m).
#pragma unroll
            for (int i = 0; i < 4; ++i)
#pragma unroll
                for (int jj = 0; jj < 4; ++jj) {
                    const int j = pass * 4 + jj;
                    bf16x4 pk = {(bf16_t)acc[i][j][0], (bf16_t)acc[i][j][1],
                                 (bf16_t)acc[i][j][2], (bf16_t)acc[i][j][3]};
                    *(bf16x4*)&Cs[(jj * 16 + lr) * 264 + wm + i * 16 + hi * 4] = pk;
                }
            __syncthreads();
#pragma unroll
            for (int it = 0; it < 4; ++it) {
                const int lrow = it * 16 + (tid >> 4);       // n-local [0,64)
                const int m0 = (tid & 15) * 16;              // m [0,256) in 16-chunks
                bf16x8 v0 = *(const bf16x8*)&Cs[lrow * 264 + m0];
                bf16x8 v1 = *(const bf16x8*)&Cs[lrow * 264 + m0 + 8];
                const int n = nt * 128 + pass * 64 + lrow;
                bf16_t* dst = g.O + (size_t)(bx * 2 + (m0 >> 7)) * g.Ob + (size_t)c * g.Oc +
                              (size_t)(n >> 5) * g.Onh + (size_t)(n & 31) * g.Onp + (m0 & 127);
                *(bf16x8*)dst = v0;
                *(bf16x8*)(dst + 8) = v1;
            }
            __syncthreads();
        }
    }
}

// ---------------------------------------------------------------------------
// Spatial attention, MFMA, one wave per (b,s,h). 24x24 padded to 32.
// ---------------------------------------------------------------------------
__global__ __launch_bounds__(256) void attn_spatial_mfma(
    const bf16_t* __restrict__ Q, const bf16_t* __restrict__ K,
    const bf16_t* __restrict__ V, bf16_t* __restrict__ O)
{
    __shared__ bf16_t Ps[4][32 * 40];
    __shared__ bf16_t Vt[4][32 * 40];

    const int tid = threadIdx.x, wv = tid >> 6, ln = tid & 63;
    const int lr = ln & 15, hi = ln >> 4, lk = hi * 8;

    const int bsh = blockIdx.x * 4 + wv;
    const int h = bsh & 7, s = (bsh >> 3) & 127, b = bsh >> 10;
    const size_t qb = (size_t)bsh * (Cn * Pn);

    {
        const int p = ln >> 1, c0 = 24 + (ln & 1) * 4;
        bf16x4 z = {};
        *(bf16x4*)&Vt[wv][p * 40 + c0] = z;
    }
#pragma unroll
    for (int it = 0; it < 2; ++it) {
        const int ch = it * 64 + ln;
        if (ch < 96) {
            const int cc = ch >> 2, p0 = (ch & 3) * 8;
            bf16x8 v = *(const bf16x8*)(V + qb + cc * 32 + p0);
#pragma unroll
            for (int j = 0; j < 8; ++j)
                Vt[wv][(p0 + j) * 40 + cc] = v[j];
        }
    }

    bf16x8 aq0 = *(const bf16x8*)(Q + qb + lr * 32 + lk);
    bf16x8 aq1 = *(const bf16x8*)(Q + qb + (16 + lr) * 32 + lk);
    bf16x8 bk0 = *(const bf16x8*)(K + qb + lr * 32 + lk);
    bf16x8 bk1 = *(const bf16x8*)(K + qb + (16 + lr) * 32 + lk);
    const f32x4 zz = {0.f, 0.f, 0.f, 0.f};
    f32x4 sc[2][2];
    sc[0][0] = __builtin_amdgcn_mfma_f32_16x16x32_bf16(aq0, bk0, zz, 0, 0, 0);
    sc[0][1] = __builtin_amdgcn_mfma_f32_16x16x32_bf16(aq0, bk1, zz, 0, 0, 0);
    sc[1][0] = __builtin_amdgcn_mfma_f32_16x16x32_bf16(aq1, bk0, zz, 0, 0, 0);
    sc[1][1] = __builtin_amdgcn_mfma_f32_16x16x32_bf16(aq1, bk1, zz, 0, 0, 0);

    const float scale = 0.17677669529663687f;
#pragma unroll
    for (int i = 0; i < 2; ++i) {
        float s0[4], s1[4], mx[4];
#pragma unroll
        for (int r = 0; r < 4; ++r) {
            s0[r] = sc[i][0][r] * scale;
            s1[r] = (lr >= 8) ? -3.0e38f : sc[i][1][r] * scale;
            mx[r] = fmaxf(s0[r], s1[r]);
        }
#pragma unroll
        for (int d = 1; d < 16; d <<= 1)
#pragma unroll
            for (int r = 0; r < 4; ++r) mx[r] = fmaxf(mx[r], __shfl_xor(mx[r], d));
        float e0[4], e1[4], sm[4];
#pragma unroll
        for (int r = 0; r < 4; ++r) {
            e0[r] = __expf(s0[r] - mx[r]);
            e1[r] = __expf(s1[r] - mx[r]);
            sm[r] = e0[r] + e1[r];
        }
#pragma unroll
        for (int d = 1; d < 16; d <<= 1)
#pragma unroll
            for (int r = 0; r < 4; ++r) sm[r] += __shfl_xor(sm[r], d);
#pragma unroll
        for (int r = 0; r < 4; ++r) {
            const float inv = 1.f / sm[r];
            const int row = i * 16 + hi * 4 + r;
            Ps[wv][row * 40 + lr]      = (bf16_t)(e0[r] * inv);
            Ps[wv][row * 40 + 16 + lr] = (bf16_t)(e1[r] * inv);
        }
    }

    bf16x8 ap0 = *(const bf16x8*)&Ps[wv][lr * 40 + lk];
    bf16x8 ap1 = *(const bf16x8*)&Ps[wv][(16 + lr) * 40 + lk];
    bf16x8 bv0 = *(const bf16x8*)&Vt[wv][lr * 40 + lk];
    bf16x8 bv1 = *(const bf16x8*)&Vt[wv][(16 + lr) * 40 + lk];
    f32x4 o[2][2];
    o[0][0] = __builtin_amdgcn_mfma_f32_16x16x32_bf16(ap0, bv0, zz, 0, 0, 0);
    o[0][1] = __builtin_amdgcn_mfma_f32_16x16x32_bf16(ap0, bv1, zz, 0, 0, 0);
    o[1][0] = __builtin_amdgcn_mfma_f32_16x16x32_bf16(ap1, bv0, zz, 0, 0, 0);
    o[1][1] = __builtin_amdgcn_mfma_f32_16x16x32_bf16(ap1, bv1, zz, 0, 0, 0);

#pragma unroll
    for (int i = 0; i < 2; ++i)
#pragma unroll
        for (int r = 0; r < 4; ++r) {
            const int c = i * 16 + hi * 4 + r;
            if (c < 24) {
                const size_t ob = ((size_t)(b * Cn + c) * Sn + s) * En + h * Pn;
#pragma unroll
                for (int j = 0; j < 2; ++j)
                    O[ob + j * 16 + lr] = (bf16_t)o[i][j][r];
            }
        }
}

// ---------------------------------------------------------------------------
// Temporal attention, MFMA. One block (4 waves) per (b,h,c).
// ---------------------------------------------------------------------------
__global__ __launch_bounds__(256) void attn_temporal_mfma(
    const bf16_t* __restrict__ Q, const bf16_t* __restrict__ K,
    const bf16_t* __restrict__ Vt, bf16_t* __restrict__ O)
{
    const int c = blockIdx.x, h = blockIdx.y, b = blockIdx.z;
    const size_t base = ((size_t)(b * Hn + h) * Cn + c) * (Sn * Pn);

    __shared__ bf16_t Qs[128 * 32];
    __shared__ bf16_t Ks[128 * 32];
    __shared__ bf16_t Vs[32 * 136];
    __shared__ bf16_t Ps[128 * 136];

    const int tid = threadIdx.x, wv = tid >> 6, ln = tid & 63;
    const int lr = ln & 15, lk = (ln >> 4) * 8;

#pragma unroll
    for (int it = 0; it < 2; ++it) {
        const int cb = it * 256 + wv * 64;
        const int mc = cb + ln;
        const int row = mc >> 2, kc = (mc & 3) * 8;
        gl2lds16(Q + base + row * 32 + kc, &Qs[cb * 8]);
        gl2lds16(K + base + row * 32 + kc, &Ks[cb * 8]);
    }
#pragma unroll
    for (int it = 0; it < 2; ++it) {
        const int mc = it * 256 + tid;
        const int p = mc >> 4, scn = (mc & 15) * 8;
        bf16x8 v = *(const bf16x8*)(Vt + base + p * 128 + scn);
        *(bf16x8*)&Vs[p * 136 + scn] = v;
    }
    __syncthreads();

    const int r0 = wv * 32;
    bf16x8 aq0 = *(const bf16x8*)&Qs[(r0 + lr) * 32 + lk];
    bf16x8 aq1 = *(const bf16x8*)&Qs[(r0 + 16 + lr) * 32 + lk];
    f32x4 sc_[2][8];
    const f32x4 zz = {0.f, 0.f, 0.f, 0.f};
#pragma unroll
    for (int j = 0; j < 8; ++j) {
        bf16x8 bk = *(const bf16x8*)&Ks[(j * 16 + lr) * 32 + lk];
        sc_[0][j] = __builtin_amdgcn_mfma_f32_16x16x32_bf16(aq0, bk, zz, 0, 0, 0);
        sc_[1][j] = __builtin_amdgcn_mfma_f32_16x16x32_bf16(aq1, bk, zz, 0, 0, 0);
    }

    const float scale = 0.17677669529663687f;
#pragma unroll
    for (int i = 0; i < 2; ++i) {
        float mx[4], sm[4];
#pragma unroll
        for (int r = 0; r < 4; ++r) {
            float m = sc_[i][0][r];
#pragma unroll
            for (int j = 1; j < 8; ++j) m = fmaxf(m, sc_[i][j][r]);
            mx[r] = m;
        }
#pragma unroll
        for (int d = 1; d < 16; d <<= 1)
#pragma unroll
            for (int r = 0; r < 4; ++r) mx[r] = fmaxf(mx[r], __shfl_xor(mx[r], d));
#pragma unroll
        for (int r = 0; r < 4; ++r) sm[r] = 0.f;
#pragma unroll
        for (int j = 0; j < 8; ++j)
#pragma unroll
            for (int r = 0; r < 4; ++r) {
                const float e = __expf((sc_[i][j][r] - mx[r]) * scale);
                sc_[i][j][r] = e; sm[r] += e;
            }
#pragma unroll
        for (int d = 1; d < 16; d <<= 1)
#pragma unroll
            for (int r = 0; r < 4; ++r) sm[r] += __shfl_xor(sm[r], d);
        float inv[4];
#pragma unroll
        for (int r = 0; r < 4; ++r) inv[r] = 1.f / sm[r];
        const int rb = r0 + i * 16 + (ln >> 4) * 4;
#pragma unroll
        for (int j = 0; j < 8; ++j)
#pragma unroll
            for (int r = 0; r < 4; ++r)
                Ps[(rb + r) * 136 + j * 16 + lr] = (bf16_t)(sc_[i][j][r] * inv[r]);
    }
    __syncthreads();

    f32x4 o[2][2] = {};
#pragma unroll
    for (int kk = 0; kk < 4; ++kk) {
        bf16x8 ap0 = *(const bf16x8*)&Ps[(r0 + lr) * 136 + kk * 32 + lk];
        bf16x8 ap1 = *(const bf16x8*)&Ps[(r0 + 16 + lr) * 136 + kk * 32 + lk];
        bf16x8 bv0 = *(const bf16x8*)&Vs[lr * 136 + kk * 32 + lk];
        bf16x8 bv1 = *(const bf16x8*)&Vs[(16 + lr) * 136 + kk * 32 + lk];
        o[0][0] = __builtin_amdgcn_mfma_f32_16x16x32_bf16(ap0, bv0, o[0][0], 0, 0, 0);
        o[0][1] = __builtin_amdgcn_mfma_f32_16x16x32_bf16(ap0, bv1, o[0][1], 0, 0, 0);
        o[1][0] = __builtin_amdgcn_mfma_f32_16x16x32_bf16(ap1, bv0, o[1][0], 0, 0, 0);
        o[1][1] = __builtin_amdgcn_mfma_f32_16x16x32_bf16(ap1, bv1, o[1][1], 0, 0, 0);
    }

#pragma unroll
    for (int i = 0; i < 2; ++i) {
        const int sb = r0 + i * 16 + (ln >> 4) * 4;
#pragma unroll
        for (int j = 0; j < 2; ++j) {
            const int p = h * 32 + j * 16 + lr;
#pragma unroll
            for (int r = 0; r < 4; ++r)
                O[((size_t)(b * Cn + c) * Sn + (sb + r)) * En + p] = (bf16_t)o[i][j][r];
        }
    }
}

// ---------------------------------------------------------------------------
// attn_out = LN(xb + spat) + LN(xb + temp)
// ---------------------------------------------------------------------------
__global__ __launch_bounds__(256) void ln_combine_k(
    const bf16_t* __restrict__ xb, const bf16_t* __restrict__ spat,
    const bf16_t* __restrict__ temp, const float* __restrict__ g,
    const float* __restrict__ beta, bf16_t* __restrict__ AO)
{
    const int row = blockIdx.x * 4 + (threadIdx.x >> 6);
    const int lane = threadIdx.x & 63;
    const size_t off = (size_t)row * En;

    float v1[4], v2[4];
    float s1 = 0, s2 = 0, q1 = 0, q2 = 0;
#pragma unroll
    for (int i = 0; i < 4; i++) {
        const int e = lane + i * 64;
        const float xv = (float)xb[off + e];
        const float a = xv + (float)spat[off + e];
        const float t = xv + (float)temp[off + e];
        v1[i] = a; v2[i] = t;
        s1 += a; s2 += t; q1 += a * a; q2 += t * t;
    }
    for (int d = 32; d; d >>= 1) {
        s1 += __shfl_xor(s1, d); s2 += __shfl_xor(s2, d);
        q1 += __shfl_xor(q1, d); q2 += __shfl_xor(q2, d);
    }
    const float mu1 = s1 / En, mu2 = s2 / En;
    const float r1 = rsqrtf(q1 / En - mu1 * mu1 + 1e-6f);
    const float r2 = rsqrtf(q2 / En - mu2 * mu2 + 1e-6f);
#pragma unroll
    for (int i = 0; i < 4; i++) {
        const int e = lane + i * 64;
        const float out = (v1[i] - mu1) * r1 * g[e] + beta[e] +
                          (v2[i] - mu2) * r2 * g[e] + beta[e];
        AO[off + e] = (bf16_t)out;
    }
}

__global__ __launch_bounds__(256) void ln_final_k(
    const bf16_t* __restrict__ AO, const bf16_t* __restrict__ FF,
    const float* __restrict__ g, const float* __restrict__ beta,
    float* __restrict__ out)
{
    const int row = blockIdx.x * 4 + (threadIdx.x >> 6);
    const int lane = threadIdx.x & 63;
    const size_t off = (size_t)row * En;

    float v[4];
    float s = 0, q = 0;
#pragma unroll
    for (int i = 0; i < 4; i++) {
        const int e = lane + i * 64;
        const float a = (float)AO[off + e] + (float)FF[off + e];
        v[i] = a; s += a; q += a * a;
    }
    for (int d = 32; d; d >>= 1) { s += __shfl_xor(s, d); q += __shfl_xor(q, d); }
    const float mu = s / En;
    const float r = rsqrtf(q / En - mu * mu + 1e-6f);
#pragma unroll
    for (int i = 0; i < 4; i++) {
        const int e = lane + i * 64;
        out[off + e] = (v[i] - mu) * r * g[e] + beta[e];
    }
}

// ---------------------------------------------------------------------------
extern "C" void kernel_launch(void* const* d_in, const int* in_sizes, int n_in,
                              void* d_out, int out_size, void* d_ws, size_t ws_size,
                              hipStream_t stream)
{
    const float* x     = (const float*)d_in[0];
    const float* Wq_s  = (const float*)d_in[1];
    const float* Wk_s  = (const float*)d_in[2];
    const float* Wv_s  = (const float*)d_in[3];
    const float* Wo_s  = (const float*)d_in[4];
    const float* Wq_t  = (const float*)d_in[5];
    const float* Wk_t  = (const float*)d_in[6];
    const float* Wv_t  = (const float*)d_in[7];
    const float* Wo_t  = (const float*)d_in[8];
    const float* ln_g  = (const float*)d_in[9];
    const float* ln_b  = (const float*)d_in[10];
    const float* ff_w1 = (const float*)d_in[11];
    const float* ff_b1 = (const float*)d_in[12];
    const float* ff_w2 = (const float*)d_in[13];
    const float* ff_b2 = (const float*)d_in[14];
    float* out = (float*)d_out;

    bf16_t* wsb = (bf16_t*)d_ws;
    bf16_t* b0 = wsb;
    bf16_t* b1 = wsb + NBUF;
    bf16_t* b2 = wsb + 2 * NBUF;
    bf16_t* b3 = wsb + 3 * NBUF;
    bf16_t* b4 = wsb + 4 * NBUF;

    // d_out doubles as scratch: xb + 8 canonical weight slots
    bf16_t* xb = (bf16_t*)d_out;
    bf16_t* wb = xb + NBUF;
    bf16_t* w_qs = wb + 0 * WSLOT;      // copy-convert slot
    bf16_t* wtr  = wb + 1 * WSLOT;      // 7 transpose slots follow
    bf16_t* w_os = wtr + 0 * WSLOT;
    bf16_t* w_qt = wtr + 1 * WSLOT;
    bf16_t* w_kt = wtr + 2 * WSLOT;
    bf16_t* w_vt = wtr + 3 * WSLOT;
    bf16_t* w_ot = wtr + 4 * WSLOT;
    bf16_t* w_f1 = wtr + 5 * WSLOT;
    bf16_t* w_f2 = wtr + 6 * WSLOT;
    bf16_t* w_ks = b4 + NBUF - 2 * 65536;   // b4 first overwritten by attn_temporal,
    bf16_t* w_vs = b4 + NBUF - 65536;       // which runs after spatial QKV consumes these

    // strides
    const int XAb = Cn * Sn * En, XAc = Sn * En, XAs = En;                          // [B,C,S,E]
    const int QSb = Sn * Hn * Cn * Pn, QSs = Hn * Cn * Pn, QSh = Cn * Pn;           // [B,S,H,C,P]
    const int QTb = Hn * Cn * Sn * Pn, QTh = Cn * Sn * Pn, QTc = Sn * Pn, QTs = Pn; // [B,H,C,S,P]
    const int WCP = 256 * 256;

    // --- conversions (source-major, coalesced) ---
    conv_x_k<<<NBUF / 1024, 256, 0, stream>>>(x, xb);
    conv_w_copy_k<<<1536, 256, 0, stream>>>(Wq_s, w_qs);
    conv_w_tr_k<<<dim3(32, 24, 7), 256, 0, stream>>>(
        TDesc{Wo_s, En * En, Pn, En},                 // [c,e,f]: g=f>>5
        TDesc{Wq_t, En * Pn, Cn * En * Pn, Pn},       // [h,c,e,p]: g=h
        TDesc{Wk_t, En * Pn, Cn * En * Pn, Pn},
        TDesc{Wv_t, En * Pn, Cn * En * Pn, Pn},
        TDesc{Wo_t, En * En, Pn, En},
        TDesc{ff_w1, En * En, Pn, En},
        TDesc{ff_w2, En * En, Pn, En},
        wtr);
    conv_w_k<<<256, 256, 0, stream>>>(Wk_s, w_ks, 0, En * Pn, 1, Pn);
    conv_w_k<<<256, 256, 0, stream>>>(Wv_s, w_vs, 0, En * Pn, 1, Pn);

    // --- spatial branch QKV + attention -> b3 ---
    gemm_mfma<3, 0><<<dim3(8, 6, 24), 256, 0, stream>>>(
        xb, XAb, XAc, XAs,
        GDesc{w_qs, b0, 0, WCP, QSb, Pn, QSs, QSh, 1, 0},
        GDesc{w_ks, b1, 0, 0,   QSb, Pn, QSs, QSh, 1, 0},
        GDesc{w_vs, b2, 0, 0,   QSb, Pn, QSs, QSh, 1, 0},
        nullptr);
    attn_spatial_mfma<<<Bn * Sn * Hn / 4, 256, 0, stream>>>(b0, b1, b2, b3);

    // --- temporal branch QKV + attention -> b4 ---
    gemm_mfma<3, 0><<<dim3(8, 6, 24), 256, 0, stream>>>(
        xb, XAb, XAc, XAs,
        GDesc{w_qt, b0, 0, WCP, QTb, QTc, QTs, QTh, 1, 0},
        GDesc{w_kt, b1, 0, WCP, QTb, QTc, QTs, QTh, 1, 0},
        GDesc{w_vt, b2, 0, WCP, QTb, QTc, 1, QTh, Sn, 1},
        nullptr);
    attn_temporal_mfma<<<dim3(24, 8, 16), 256, 0, stream>>>(b0, b1, b2, b4);

    // --- fused output projections: Wo_s(b3)->b0, Wo_t(b4)->b1 (NP=2, Aoff) ---
    gemm_mfma<2, 0><<<dim3(8, 4, 24), 256, 0, stream>>>(
        b3, XAb, XAc, XAs,
        GDesc{w_os, b0, 0,          WCP, XAb, XAc, XAs, 32, 1, 0},
        GDesc{w_ot, b1, (int)NBUF,  WCP, XAb, XAc, XAs, 32, 1, 0},
        GDesc{w_os, b0, 0,          WCP, XAb, XAc, XAs, 32, 1, 0}, nullptr);

    // --- combine + FF + final LN ---
    ln_combine_k<<<NROWS / 4, 256, 0, stream>>>(xb, b0, b1, ln_g, ln_b, b2);
    gemm_mfma<1, 1><<<dim3(8, 2, 24), 256, 0, stream>>>(
        b2, XAb, XAc, XAs,
        GDesc{w_f1, b3, 0, WCP, XAb, XAc, XAs, 32, 1, 0},
        GDesc{w_f1, b3, 0, WCP, XAb, XAc, XAs, 32, 1, 0},
        GDesc{w_f1, b3, 0, WCP, XAb, XAc, XAs, 32, 1, 0}, ff_b1);
    gemm_mfma<1, 2><<<dim3(8, 2, 24), 256, 0, stream>>>(
        b3, XAb, XAc, XAs,
        GDesc{w_f2, b4, 0, WCP, XAb, XAc, XAs, 32, 1, 0},
        GDesc{w_f2, b4, 0, WCP, XAb, XAc, XAs, 32, 1, 0},
        GDesc{w_f2, b4, 0, WCP, XAb, XAc, XAs, 32, 1, 0}, ff_b2);
    ln_final_k<<<NROWS / 4, 256, 0, stream>>>(b2, b4, ln_g, ln_b, out);
}

// Round 4
// 388.373 us; speedup vs baseline: 1.0297x; 1.0297x over previous
//
#include <hip/hip_runtime.h>
#include <hip/hip_bf16.h>

constexpr int Bn = 16, Cn = 24, Sn = 128, En = 256, Hn = 8, Pn = 32;
constexpr int NROWS = Bn * Cn * Sn;                  // 49152
constexpr size_t NBUF = (size_t)Bn * Cn * Sn * En;   // 12,582,912 elems
constexpr size_t WSLOT = (size_t)Cn * 256 * 256;     // 1,572,864

typedef __bf16 bf16_t;
typedef bf16_t bf16x8 __attribute__((ext_vector_type(8)));
typedef bf16_t bf16x4 __attribute__((ext_vector_type(4)));
typedef float f32x4 __attribute__((ext_vector_type(4)));

// global -> LDS direct 16B copy (dest = wave-uniform base + lane*16)
__device__ __forceinline__ void gl2lds16(const bf16_t* g, bf16_t* l) {
    typedef const __attribute__((address_space(1))) unsigned int* gp_t;
    typedef __attribute__((address_space(3))) unsigned int* lp_t;
    __builtin_amdgcn_global_load_lds((gp_t)(unsigned long long)g,
                                     (lp_t)(unsigned int)(unsigned long long)l,
                                     16, 0, 0);
}

// ---------------------------------------------------------------------------
// x fp32 -> bf16
// ---------------------------------------------------------------------------
__global__ __launch_bounds__(256) void conv_x_k(const float* __restrict__ x,
                                                bf16_t* __restrict__ xb) {
    const size_t i = ((size_t)blockIdx.x * 256 + threadIdx.x) * 4;
    const float4 v = *(const float4*)(x + i);
    bf16x4 o = {(bf16_t)v.x, (bf16_t)v.y, (bf16_t)v.z, (bf16_t)v.w};
    *(bf16x4*)(xb + i) = o;
}

// ---------------------------------------------------------------------------
// Wq_s copy-convert (source already e-contiguous): [h,c,p,e] -> [c][n=h*32+p][e]
// ---------------------------------------------------------------------------
__global__ __launch_bounds__(256) void conv_w_copy_k(const float* __restrict__ W,
                                                     bf16_t* __restrict__ out) {
    const int row = blockIdx.x * 4 + (threadIdx.x >> 6);   // c*256+n
    const int lane = threadIdx.x & 63;
    const int n = row & 255, c = row >> 8;
    const float* src = W + (size_t)c * (Pn * En) + (size_t)(n >> 5) * (Cn * Pn * En) +
                       (size_t)(n & 31) * En + lane * 4;
    const float4 v = *(const float4*)src;
    bf16x4 o = {(bf16_t)v.x, (bf16_t)v.y, (bf16_t)v.z, (bf16_t)v.w};
    *(bf16x4*)(out + (size_t)row * 256 + lane * 4) = o;
}

// ---------------------------------------------------------------------------
// Transpose-convert for the 7 e-strided weights -> canonical [slot][c][n][e].
// ---------------------------------------------------------------------------
struct TDesc { const float* W; int Sc, Snh, Se; };

__global__ __launch_bounds__(256) void conv_w_tr_k(
    TDesc d0, TDesc d1, TDesc d2, TDesc d3, TDesc d4, TDesc d5, TDesc d6,
    bf16_t* __restrict__ out)
{
    TDesc d;
    switch (blockIdx.z) {
        case 0: d = d0; break; case 1: d = d1; break; case 2: d = d2; break;
        case 3: d = d3; break; case 4: d = d4; break; case 5: d = d5; break;
        default: d = d6; break;
    }
    const int g = blockIdx.x & 7, et = blockIdx.x >> 3;
    const int c = blockIdx.y;

    __shared__ float tile[32][65];

    const int t = threadIdx.x;
    const float* base = d.W + (size_t)c * d.Sc + (size_t)g * d.Snh;

#pragma unroll
    for (int pass = 0; pass < 2; ++pass) {
        const int e_local = pass * 32 + (t >> 3);
        const int j4 = (t & 7) * 4;
        const float4 v = *(const float4*)(base + (size_t)(et * 64 + e_local) * d.Se + j4);
        tile[j4 + 0][e_local] = v.x;
        tile[j4 + 1][e_local] = v.y;
        tile[j4 + 2][e_local] = v.z;
        tile[j4 + 3][e_local] = v.w;
    }
    __syncthreads();

    const int j = t >> 3, e8 = (t & 7) * 8;
    bf16x8 o;
#pragma unroll
    for (int k = 0; k < 8; ++k) o[k] = (bf16_t)tile[j][e8 + k];
    *(bf16x8*)(out + (size_t)blockIdx.z * WSLOT +
               ((size_t)c * 256 + g * 32 + j) * 256 + et * 64 + e8) = o;
}

// small shared spatial k/v weights (tiny: 64 KB each)
__global__ __launch_bounds__(256) void conv_w_k(const float* __restrict__ W,
                                                bf16_t* __restrict__ Wb,
                                                int Sc, int Snh, int Snp, int Se) {
    const int n = blockIdx.x & 255, c = blockIdx.x >> 8;
    const int e = threadIdx.x;
    Wb[(size_t)blockIdx.x * 256 + e] =
        (bf16_t)W[(size_t)c * Sc + (size_t)(n >> 5) * Snh + (n & 31) * Snp + (size_t)e * Se];
}

// ---------------------------------------------------------------------------
// bf16 MFMA GEMM, up to 3 fused projections sharing A, LDS-staged epilogue.
// K-loop = counted-vmcnt pipeline (T3+T4): 3 LDS buffers, depth-2 prefetch,
// s_waitcnt vmcnt(8) steady state (4 load-insts/wave/stage), never 0 in loop.
// Bank-conflict fix (T2, both-sides-or-neither): physical 16B chunk j of row r
// holds logical chunk j^((r>>1)&3). Applied by permuting the GLOBAL source kc
// in stage() (LDS dest of global_load_lds stays linear) and XORing the same
// term into the fragment ds_read address. Collapses the 8-way alias (64B row
// stride mod 128B bank cycle) to 2-way (free).
// trans=0: output n-inner; trans=1: output m-inner (16B stores along m).
// EPI: 0 / 1 (bias+relu) / 2 (bias)  (trans=0 path only)
// ---------------------------------------------------------------------------
struct GDesc { const bf16_t* W; bf16_t* O; int Aoff, Wc, Ob, Oc, Os, Onh, Onp, trans; };

template <int NP, int EPI>
__global__ __launch_bounds__(256) void gemm_mfma(
    const bf16_t* __restrict__ A, int Ab, int Ac, int As,
    GDesc g0, GDesc g1, GDesc g2, const float* __restrict__ bias)
{
    const int b = blockIdx.x, c = blockIdx.z;
    const int proj = (NP == 1) ? 0 : ((int)blockIdx.y >> 1);
    const int nt = (NP == 1) ? (int)blockIdx.y : ((int)blockIdx.y & 1);
    GDesc g = (proj == 0) ? g0 : (proj == 1) ? g1 : g2;

    __shared__ bf16_t smem[3][2][128 * 32];   // 3 bufs x (A,B) tiles, 48 KB
    bf16_t* Cs = &smem[0][0][0];              // epilogue staging (17408 B, aliased)

    const int tid = threadIdx.x, wv = tid >> 6, ln = tid & 63;
    const int wm = (wv >> 1) * 64, wn = (wv & 1) * 64;
    const int lr = ln & 15, hi = ln >> 4;

    const bf16_t* Abase = A + g.Aoff + (size_t)b * Ab + (size_t)c * Ac;
    const bf16_t* Bbase = g.W + (size_t)c * g.Wc + (size_t)(nt * 128) * 256;

    // stage tile kt (128x32 A + 128x32 B, 16 KB) into buffer `buf`; 4 insts/wave
    // Source chunk is pre-swizzled so the linear LDS write lands swizzled.
    auto stage = [&](int buf, int kt) {
        const int k0 = kt * 32;
#pragma unroll
        for (int it = 0; it < 2; ++it) {
            const int cb = it * 256 + wv * 64;
            const int mc = cb + ln;
            const int row = mc >> 2;
            const int kc = (((mc & 3) ^ ((row >> 1) & 3)) * 8);
            gl2lds16(Abase + (size_t)row * As + k0 + kc, &smem[buf][0][cb * 8]);
            gl2lds16(Bbase + (size_t)row * 256 + k0 + kc, &smem[buf][1][cb * 8]);
        }
    };

    f32x4 acc[4][4] = {};

    stage(0, 0);               // tile 0 -> buf 0   (4 vm-insts/wave)
    stage(1, 1);               // tile 1 -> buf 1   (8 outstanding)

#pragma unroll
    for (int kt = 0; kt < 8; ++kt) {
        if (kt < 6) stage((kt + 2) % 3, kt + 2);   // tile kt+2 -> buf (kt+2)%3
        // drain only tile kt's 4 loads; keep the younger 8 (or 4/0 at tail)
        if (kt < 6)       asm volatile("s_waitcnt vmcnt(8)" ::: "memory");
        else if (kt == 6) asm volatile("s_waitcnt vmcnt(4)" ::: "memory");
        else              asm volatile("s_waitcnt vmcnt(0)" ::: "memory");
        __builtin_amdgcn_s_barrier();              // buf kt%3 fully loaded
        __builtin_amdgcn_sched_barrier(0);

        const int cur = kt % 3;
        bf16x8 af[4], bfr[4];
#pragma unroll
        for (int i = 0; i < 4; ++i) {
            const int r = wm + i * 16 + lr;
            af[i] = *(const bf16x8*)&smem[cur][0][r * 32 + ((hi ^ ((r >> 1) & 3)) * 8)];
        }
#pragma unroll
        for (int j = 0; j < 4; ++j) {
            const int r = wn + j * 16 + lr;
            bfr[j] = *(const bf16x8*)&smem[cur][1][r * 32 + ((hi ^ ((r >> 1) & 3)) * 8)];
        }
        __builtin_amdgcn_s_setprio(1);
#pragma unroll
        for (int i = 0; i < 4; ++i)
#pragma unroll
            for (int j = 0; j < 4; ++j)
                acc[i][j] = __builtin_amdgcn_mfma_f32_16x16x32_bf16(af[i], bfr[j], acc[i][j], 0, 0, 0);
        __builtin_amdgcn_s_setprio(0);

        __builtin_amdgcn_sched_barrier(0);
        __builtin_amdgcn_s_barrier();              // protect buf cur before rewrite
    }

    // ---- LDS-staged epilogue (Cs aliases smem; vmcnt drained at kt=7) ----
#pragma unroll
    for (int pass = 0; pass < 2; ++pass) {
        if (!g.trans) {
            if (wm == pass * 64) {
#pragma unroll
                for (int i = 0; i < 4; ++i)
#pragma unroll
                    for (int j = 0; j < 4; ++j) {
                        const int n = nt * 128 + wn + j * 16 + lr;
                        float bv = 0.f;
                        if (EPI) bv = bias[c * 256 + n];
#pragma unroll
                        for (int r = 0; r < 4; ++r) {
                            float v = acc[i][j][r];
                            if (EPI) { v += bv; if (EPI == 1) v = fmaxf(v, 0.f); }
                            Cs[(i * 16 + hi * 4 + r) * 136 + wn + j * 16 + lr] = (bf16_t)v;
                        }
                    }
            }
            __syncthreads();
#pragma unroll
            for (int it = 0; it < 2; ++it) {
                const int lrow = it * 32 + (tid >> 3);
                const int n0 = (tid & 7) * 16;
                bf16x8 v0 = *(const bf16x8*)&Cs[lrow * 136 + n0];
                bf16x8 v1 = *(const bf16x8*)&Cs[lrow * 136 + n0 + 8];
                const int m = pass * 64 + lrow;
                const int n = nt * 128 + n0;
                bf16_t* dst = g.O + (size_t)b * g.Ob + (size_t)c * g.Oc +
                              (size_t)m * g.Os + (size_t)(n >> 5) * g.Onh + (n & 31);
                *(bf16x8*)dst = v0;
                *(bf16x8*)(dst + 8) = v1;
            }
            __syncthreads();
        } else {
            if (wn == pass * 64) {
#pragma unroll
                for (int i = 0; i < 4; ++i)
#pragma unroll
                    for (int j = 0; j < 4; ++j) {
                        bf16x4 pk = {(bf16_t)acc[i][j][0], (bf16_t)acc[i][j][1],
                                     (bf16_t)acc[i][j][2], (bf16_t)acc[i][j][3]};
                        *(bf16x4*)&Cs[(j * 16 + lr) * 136 + wm + i * 16 + hi * 4] = pk;
                    }
            }
            __syncthreads();
#pragma unroll
            for (int it = 0; it < 2; ++it) {
                const int lrow = it * 32 + (tid >> 3);
                const int m0 = (tid & 7) * 16;
                bf16x8 v0 = *(const bf16x8*)&Cs[lrow * 136 + m0];
                bf16x8 v1 = *(const bf16x8*)&Cs[lrow * 136 + m0 + 8];
                const int n = nt * 128 + pass * 64 + lrow;
                bf16_t* dst = g.O + (size_t)b * g.Ob + (size_t)c * g.Oc +
                              (size_t)(n >> 5) * g.Onh + (size_t)(n & 31) * g.Onp + m0;
                *(bf16x8*)dst = v0;
                *(bf16x8*)(dst + 8) = v1;
            }
            __syncthreads();
        }
    }
}

// ---------------------------------------------------------------------------
// Spatial attention, MFMA, one wave per (b,s,h). 24x24 padded to 32.
// ---------------------------------------------------------------------------
__global__ __launch_bounds__(256) void attn_spatial_mfma(
    const bf16_t* __restrict__ Q, const bf16_t* __restrict__ K,
    const bf16_t* __restrict__ V, bf16_t* __restrict__ O)
{
    __shared__ bf16_t Ps[4][32 * 40];
    __shared__ bf16_t Vt[4][32 * 40];

    const int tid = threadIdx.x, wv = tid >> 6, ln = tid & 63;
    const int lr = ln & 15, hi = ln >> 4, lk = hi * 8;

    const int bsh = blockIdx.x * 4 + wv;
    const int h = bsh & 7, s = (bsh >> 3) & 127, b = bsh >> 10;
    const size_t qb = (size_t)bsh * (Cn * Pn);

    {
        const int p = ln >> 1, c0 = 24 + (ln & 1) * 4;
        bf16x4 z = {};
        *(bf16x4*)&Vt[wv][p * 40 + c0] = z;
    }
#pragma unroll
    for (int it = 0; it < 2; ++it) {
        const int ch = it * 64 + ln;
        if (ch < 96) {
            const int cc = ch >> 2, p0 = (ch & 3) * 8;
            bf16x8 v = *(const bf16x8*)(V + qb + cc * 32 + p0);
#pragma unroll
            for (int j = 0; j < 8; ++j)
                Vt[wv][(p0 + j) * 40 + cc] = v[j];
        }
    }

    bf16x8 aq0 = *(const bf16x8*)(Q + qb + lr * 32 + lk);
    bf16x8 aq1 = *(const bf16x8*)(Q + qb + (16 + lr) * 32 + lk);
    bf16x8 bk0 = *(const bf16x8*)(K + qb + lr * 32 + lk);
    bf16x8 bk1 = *(const bf16x8*)(K + qb + (16 + lr) * 32 + lk);
    const f32x4 zz = {0.f, 0.f, 0.f, 0.f};
    f32x4 sc[2][2];
    sc[0][0] = __builtin_amdgcn_mfma_f32_16x16x32_bf16(aq0, bk0, zz, 0, 0, 0);
    sc[0][1] = __builtin_amdgcn_mfma_f32_16x16x32_bf16(aq0, bk1, zz, 0, 0, 0);
    sc[1][0] = __builtin_amdgcn_mfma_f32_16x16x32_bf16(aq1, bk0, zz, 0, 0, 0);
    sc[1][1] = __builtin_amdgcn_mfma_f32_16x16x32_bf16(aq1, bk1, zz, 0, 0, 0);

    const float scale = 0.17677669529663687f;
#pragma unroll
    for (int i = 0; i < 2; ++i) {
        float s0[4], s1[4], mx[4];
#pragma unroll
        for (int r = 0; r < 4; ++r) {
            s0[r] = sc[i][0][r] * scale;
            s1[r] = (lr >= 8) ? -3.0e38f : sc[i][1][r] * scale;
            mx[r] = fmaxf(s0[r], s1[r]);
        }
#pragma unroll
        for (int d = 1; d < 16; d <<= 1)
#pragma unroll
            for (int r = 0; r < 4; ++r) mx[r] = fmaxf(mx[r], __shfl_xor(mx[r], d));
        float e0[4], e1[4], sm[4];
#pragma unroll
        for (int r = 0; r < 4; ++r) {
            e0[r] = __expf(s0[r] - mx[r]);
            e1[r] = __expf(s1[r] - mx[r]);
            sm[r] = e0[r] + e1[r];
        }
#pragma unroll
        for (int d = 1; d < 16; d <<= 1)
#pragma unroll
            for (int r = 0; r < 4; ++r) sm[r] += __shfl_xor(sm[r], d);
#pragma unroll
        for (int r = 0; r < 4; ++r) {
            const float inv = 1.f / sm[r];
            const int row = i * 16 + hi * 4 + r;
            Ps[wv][row * 40 + lr]      = (bf16_t)(e0[r] * inv);
            Ps[wv][row * 40 + 16 + lr] = (bf16_t)(e1[r] * inv);
        }
    }

    bf16x8 ap0 = *(const bf16x8*)&Ps[wv][lr * 40 + lk];
    bf16x8 ap1 = *(const bf16x8*)&Ps[wv][(16 + lr) * 40 + lk];
    bf16x8 bv0 = *(const bf16x8*)&Vt[wv][lr * 40 + lk];
    bf16x8 bv1 = *(const bf16x8*)&Vt[wv][(16 + lr) * 40 + lk];
    f32x4 o[2][2];
    o[0][0] = __builtin_amdgcn_mfma_f32_16x16x32_bf16(ap0, bv0, zz, 0, 0, 0);
    o[0][1] = __builtin_amdgcn_mfma_f32_16x16x32_bf16(ap0, bv1, zz, 0, 0, 0);
    o[1][0] = __builtin_amdgcn_mfma_f32_16x16x32_bf16(ap1, bv0, zz, 0, 0, 0);
    o[1][1] = __builtin_amdgcn_mfma_f32_16x16x32_bf16(ap1, bv1, zz, 0, 0, 0);

#pragma unroll
    for (int i = 0; i < 2; ++i)
#pragma unroll
        for (int r = 0; r < 4; ++r) {
            const int c = i * 16 + hi * 4 + r;
            if (c < 24) {
                const size_t ob = ((size_t)(b * Cn + c) * Sn + s) * En + h * Pn;
#pragma unroll
                for (int j = 0; j < 2; ++j)
                    O[ob + j * 16 + lr] = (bf16_t)o[i][j][r];
            }
        }
}

// ---------------------------------------------------------------------------
// Temporal attention, MFMA. One block (4 waves) per (b,h,c).
// ---------------------------------------------------------------------------
__global__ __launch_bounds__(256) void attn_temporal_mfma(
    const bf16_t* __restrict__ Q, const bf16_t* __restrict__ K,
    const bf16_t* __restrict__ Vt, bf16_t* __restrict__ O)
{
    const int c = blockIdx.x, h = blockIdx.y, b = blockIdx.z;
    const size_t base = ((size_t)(b * Hn + h) * Cn + c) * (Sn * Pn);

    __shared__ bf16_t Qs[128 * 32];
    __shared__ bf16_t Ks[128 * 32];
    __shared__ bf16_t Vs[32 * 136];
    __shared__ bf16_t Ps[128 * 136];

    const int tid = threadIdx.x, wv = tid >> 6, ln = tid & 63;
    const int lr = ln & 15, lk = (ln >> 4) * 8;

#pragma unroll
    for (int it = 0; it < 2; ++it) {
        const int cb = it * 256 + wv * 64;
        const int mc = cb + ln;
        const int row = mc >> 2, kc = (mc & 3) * 8;
        gl2lds16(Q + base + row * 32 + kc, &Qs[cb * 8]);
        gl2lds16(K + base + row * 32 + kc, &Ks[cb * 8]);
    }
#pragma unroll
    for (int it = 0; it < 2; ++it) {
        const int mc = it * 256 + tid;
        const int p = mc >> 4, scn = (mc & 15) * 8;
        bf16x8 v = *(const bf16x8*)(Vt + base + p * 128 + scn);
        *(bf16x8*)&Vs[p * 136 + scn] = v;
    }
    __syncthreads();

    const int r0 = wv * 32;
    bf16x8 aq0 = *(const bf16x8*)&Qs[(r0 + lr) * 32 + lk];
    bf16x8 aq1 = *(const bf16x8*)&Qs[(r0 + 16 + lr) * 32 + lk];
    f32x4 sc_[2][8];
    const f32x4 zz = {0.f, 0.f, 0.f, 0.f};
#pragma unroll
    for (int j = 0; j < 8; ++j) {
        bf16x8 bk = *(const bf16x8*)&Ks[(j * 16 + lr) * 32 + lk];
        sc_[0][j] = __builtin_amdgcn_mfma_f32_16x16x32_bf16(aq0, bk, zz, 0, 0, 0);
        sc_[1][j] = __builtin_amdgcn_mfma_f32_16x16x32_bf16(aq1, bk, zz, 0, 0, 0);
    }

    const float scale = 0.17677669529663687f;
#pragma unroll
    for (int i = 0; i < 2; ++i) {
        float mx[4], sm[4];
#pragma unroll
        for (int r = 0; r < 4; ++r) {
            float m = sc_[i][0][r];
#pragma unroll
            for (int j = 1; j < 8; ++j) m = fmaxf(m, sc_[i][j][r]);
            mx[r] = m;
        }
#pragma unroll
        for (int d = 1; d < 16; d <<= 1)
#pragma unroll
            for (int r = 0; r < 4; ++r) mx[r] = fmaxf(mx[r], __shfl_xor(mx[r], d));
#pragma unroll
        for (int r = 0; r < 4; ++r) sm[r] = 0.f;
#pragma unroll
        for (int j = 0; j < 8; ++j)
#pragma unroll
            for (int r = 0; r < 4; ++r) {
                const float e = __expf((sc_[i][j][r] - mx[r]) * scale);
                sc_[i][j][r] = e; sm[r] += e;
            }
#pragma unroll
        for (int d = 1; d < 16; d <<= 1)
#pragma unroll
            for (int r = 0; r < 4; ++r) sm[r] += __shfl_xor(sm[r], d);
        float inv[4];
#pragma unroll
        for (int r = 0; r < 4; ++r) inv[r] = 1.f / sm[r];
        const int rb = r0 + i * 16 + (ln >> 4) * 4;
#pragma unroll
        for (int j = 0; j < 8; ++j)
#pragma unroll
            for (int r = 0; r < 4; ++r)
                Ps[(rb + r) * 136 + j * 16 + lr] = (bf16_t)(sc_[i][j][r] * inv[r]);
    }
    __syncthreads();

    f32x4 o[2][2] = {};
#pragma unroll
    for (int kk = 0; kk < 4; ++kk) {
        bf16x8 ap0 = *(const bf16x8*)&Ps[(r0 + lr) * 136 + kk * 32 + lk];
        bf16x8 ap1 = *(const bf16x8*)&Ps[(r0 + 16 + lr) * 136 + kk * 32 + lk];
        bf16x8 bv0 = *(const bf16x8*)&Vs[lr * 136 + kk * 32 + lk];
        bf16x8 bv1 = *(const bf16x8*)&Vs[(16 + lr) * 136 + kk * 32 + lk];
        o[0][0] = __builtin_amdgcn_mfma_f32_16x16x32_bf16(ap0, bv0, o[0][0], 0, 0, 0);
        o[0][1] = __builtin_amdgcn_mfma_f32_16x16x32_bf16(ap0, bv1, o[0][1], 0, 0, 0);
        o[1][0] = __builtin_amdgcn_mfma_f32_16x16x32_bf16(ap1, bv0, o[1][0], 0, 0, 0);
        o[1][1] = __builtin_amdgcn_mfma_f32_16x16x32_bf16(ap1, bv1, o[1][1], 0, 0, 0);
    }

#pragma unroll
    for (int i = 0; i < 2; ++i) {
        const int sb = r0 + i * 16 + (ln >> 4) * 4;
#pragma unroll
        for (int j = 0; j < 2; ++j) {
            const int p = h * 32 + j * 16 + lr;
#pragma unroll
            for (int r = 0; r < 4; ++r)
                O[((size_t)(b * Cn + c) * Sn + (sb + r)) * En + p] = (bf16_t)o[i][j][r];
        }
    }
}

// ---------------------------------------------------------------------------
// attn_out = LN(xb + spat) + LN(xb + temp)
// ---------------------------------------------------------------------------
__global__ __launch_bounds__(256) void ln_combine_k(
    const bf16_t* __restrict__ xb, const bf16_t* __restrict__ spat,
    const bf16_t* __restrict__ temp, const float* __restrict__ g,
    const float* __restrict__ beta, bf16_t* __restrict__ AO)
{
    const int row = blockIdx.x * 4 + (threadIdx.x >> 6);
    const int lane = threadIdx.x & 63;
    const size_t off = (size_t)row * En;

    float v1[4], v2[4];
    float s1 = 0, s2 = 0, q1 = 0, q2 = 0;
#pragma unroll
    for (int i = 0; i < 4; i++) {
        const int e = lane + i * 64;
        const float xv = (float)xb[off + e];
        const float a = xv + (float)spat[off + e];
        const float t = xv + (float)temp[off + e];
        v1[i] = a; v2[i] = t;
        s1 += a; s2 += t; q1 += a * a; q2 += t * t;
    }
    for (int d = 32; d; d >>= 1) {
        s1 += __shfl_xor(s1, d); s2 += __shfl_xor(s2, d);
        q1 += __shfl_xor(q1, d); q2 += __shfl_xor(q2, d);
    }
    const float mu1 = s1 / En, mu2 = s2 / En;
    const float r1 = rsqrtf(q1 / En - mu1 * mu1 + 1e-6f);
    const float r2 = rsqrtf(q2 / En - mu2 * mu2 + 1e-6f);
#pragma unroll
    for (int i = 0; i < 4; i++) {
        const int e = lane + i * 64;
        const float out = (v1[i] - mu1) * r1 * g[e] + beta[e] +
                          (v2[i] - mu2) * r2 * g[e] + beta[e];
        AO[off + e] = (bf16_t)out;
    }
}

__global__ __launch_bounds__(256) void ln_final_k(
    const bf16_t* __restrict__ AO, const bf16_t* __restrict__ FF,
    const float* __restrict__ g, const float* __restrict__ beta,
    float* __restrict__ out)
{
    const int row = blockIdx.x * 4 + (threadIdx.x >> 6);
    const int lane = threadIdx.x & 63;
    const size_t off = (size_t)row * En;

    float v[4];
    float s = 0, q = 0;
#pragma unroll
    for (int i = 0; i < 4; i++) {
        const int e = lane + i * 64;
        const float a = (float)AO[off + e] + (float)FF[off + e];
        v[i] = a; s += a; q += a * a;
    }
    for (int d = 32; d; d >>= 1) { s += __shfl_xor(s, d); q += __shfl_xor(q, d); }
    const float mu = s / En;
    const float r = rsqrtf(q / En - mu * mu + 1e-6f);
#pragma unroll
    for (int i = 0; i < 4; i++) {
        const int e = lane + i * 64;
        out[off + e] = (v[i] - mu) * r * g[e] + beta[e];
    }
}

// ---------------------------------------------------------------------------
extern "C" void kernel_launch(void* const* d_in, const int* in_sizes, int n_in,
                              void* d_out, int out_size, void* d_ws, size_t ws_size,
                              hipStream_t stream)
{
    const float* x     = (const float*)d_in[0];
    const float* Wq_s  = (const float*)d_in[1];
    const float* Wk_s  = (const float*)d_in[2];
    const float* Wv_s  = (const float*)d_in[3];
    const float* Wo_s  = (const float*)d_in[4];
    const float* Wq_t  = (const float*)d_in[5];
    const float* Wk_t  = (const float*)d_in[6];
    const float* Wv_t  = (const float*)d_in[7];
    const float* Wo_t  = (const float*)d_in[8];
    const float* ln_g  = (const float*)d_in[9];
    const float* ln_b  = (const float*)d_in[10];
    const float* ff_w1 = (const float*)d_in[11];
    const float* ff_b1 = (const float*)d_in[12];
    const float* ff_w2 = (const float*)d_in[13];
    const float* ff_b2 = (const float*)d_in[14];
    float* out = (float*)d_out;

    bf16_t* wsb = (bf16_t*)d_ws;
    bf16_t* b0 = wsb;
    bf16_t* b1 = wsb + NBUF;
    bf16_t* b2 = wsb + 2 * NBUF;
    bf16_t* b3 = wsb + 3 * NBUF;
    bf16_t* b4 = wsb + 4 * NBUF;

    // d_out doubles as scratch: xb + 8 canonical weight slots
    bf16_t* xb = (bf16_t*)d_out;
    bf16_t* wb = xb + NBUF;
    bf16_t* w_qs = wb + 0 * WSLOT;      // copy-convert slot
    bf16_t* wtr  = wb + 1 * WSLOT;      // 7 transpose slots follow
    bf16_t* w_os = wtr + 0 * WSLOT;
    bf16_t* w_qt = wtr + 1 * WSLOT;
    bf16_t* w_kt = wtr + 2 * WSLOT;
    bf16_t* w_vt = wtr + 3 * WSLOT;
    bf16_t* w_ot = wtr + 4 * WSLOT;
    bf16_t* w_f1 = wtr + 5 * WSLOT;
    bf16_t* w_f2 = wtr + 6 * WSLOT;
    bf16_t* w_ks = b4 + NBUF - 2 * 65536;   // b4 first overwritten by attn_temporal,
    bf16_t* w_vs = b4 + NBUF - 65536;       // which runs after spatial QKV consumes these

    // strides
    const int XAb = Cn * Sn * En, XAc = Sn * En, XAs = En;                          // [B,C,S,E]
    const int QSb = Sn * Hn * Cn * Pn, QSs = Hn * Cn * Pn, QSh = Cn * Pn;           // [B,S,H,C,P]
    const int QTb = Hn * Cn * Sn * Pn, QTh = Cn * Sn * Pn, QTc = Sn * Pn, QTs = Pn; // [B,H,C,S,P]
    const int WCP = 256 * 256;

    // --- conversions (source-major, coalesced) ---
    conv_x_k<<<NBUF / 1024, 256, 0, stream>>>(x, xb);
    conv_w_copy_k<<<1536, 256, 0, stream>>>(Wq_s, w_qs);
    conv_w_tr_k<<<dim3(32, 24, 7), 256, 0, stream>>>(
        TDesc{Wo_s, En * En, Pn, En},                 // [c,e,f]: g=f>>5
        TDesc{Wq_t, En * Pn, Cn * En * Pn, Pn},       // [h,c,e,p]: g=h
        TDesc{Wk_t, En * Pn, Cn * En * Pn, Pn},
        TDesc{Wv_t, En * Pn, Cn * En * Pn, Pn},
        TDesc{Wo_t, En * En, Pn, En},
        TDesc{ff_w1, En * En, Pn, En},
        TDesc{ff_w2, En * En, Pn, En},
        wtr);
    conv_w_k<<<256, 256, 0, stream>>>(Wk_s, w_ks, 0, En * Pn, 1, Pn);
    conv_w_k<<<256, 256, 0, stream>>>(Wv_s, w_vs, 0, En * Pn, 1, Pn);

    // --- spatial branch QKV + attention -> b3 ---
    gemm_mfma<3, 0><<<dim3(16, 6, 24), 256, 0, stream>>>(
        xb, XAb, XAc, XAs,
        GDesc{w_qs, b0, 0, WCP, QSb, Pn, QSs, QSh, 1, 0},
        GDesc{w_ks, b1, 0, 0,   QSb, Pn, QSs, QSh, 1, 0},
        GDesc{w_vs, b2, 0, 0,   QSb, Pn, QSs, QSh, 1, 0},
        nullptr);
    attn_spatial_mfma<<<Bn * Sn * Hn / 4, 256, 0, stream>>>(b0, b1, b2, b3);

    // --- temporal branch QKV + attention -> b4 ---
    gemm_mfma<3, 0><<<dim3(16, 6, 24), 256, 0, stream>>>(
        xb, XAb, XAc, XAs,
        GDesc{w_qt, b0, 0, WCP, QTb, QTc, QTs, QTh, 1, 0},
        GDesc{w_kt, b1, 0, WCP, QTb, QTc, QTs, QTh, 1, 0},
        GDesc{w_vt, b2, 0, WCP, QTb, QTc, 1, QTh, Sn, 1},
        nullptr);
    attn_temporal_mfma<<<dim3(24, 8, 16), 256, 0, stream>>>(b0, b1, b2, b4);

    // --- fused output projections: Wo_s(b3)->b0, Wo_t(b4)->b1 (NP=2, Aoff) ---
    gemm_mfma<2, 0><<<dim3(16, 4, 24), 256, 0, stream>>>(
        b3, XAb, XAc, XAs,
        GDesc{w_os, b0, 0,          WCP, XAb, XAc, XAs, 32, 1, 0},
        GDesc{w_ot, b1, (int)NBUF,  WCP, XAb, XAc, XAs, 32, 1, 0},
        GDesc{w_os, b0, 0,          WCP, XAb, XAc, XAs, 32, 1, 0}, nullptr);

    // --- combine + FF + final LN ---
    ln_combine_k<<<NROWS / 4, 256, 0, stream>>>(xb, b0, b1, ln_g, ln_b, b2);
    gemm_mfma<1, 1><<<dim3(16, 2, 24), 256, 0, stream>>>(
        b2, XAb, XAc, XAs,
        GDesc{w_f1, b3, 0, WCP, XAb, XAc, XAs, 32, 1, 0},
        GDesc{w_f1, b3, 0, WCP, XAb, XAc, XAs, 32, 1, 0},
        GDesc{w_f1, b3, 0, WCP, XAb, XAc, XAs, 32, 1, 0}, ff_b1);
    gemm_mfma<1, 2><<<dim3(16, 2, 24), 256, 0, stream>>>(
        b3, XAb, XAc, XAs,
        GDesc{w_f2, b4, 0, WCP, XAb, XAc, XAs, 32, 1, 0},
        GDesc{w_f2, b4, 0, WCP, XAb, XAc, XAs, 32, 1, 0},
        GDesc{w_f2, b4, 0, WCP, XAb, XAc, XAs, 32, 1, 0}, ff_b2);
    ln_final_k<<<NROWS / 4, 256, 0, stream>>>(b2, b4, ln_g, ln_b, out);
}

// Round 5
// 387.322 us; speedup vs baseline: 1.0325x; 1.0027x over previous
//
#include <hip/hip_runtime.h>
#include <hip/hip_bf16.h>

constexpr int Bn = 16, Cn = 24, Sn = 128, En = 256, Hn = 8, Pn = 32;
constexpr size_t NBUF = (size_t)Bn * Cn * Sn * En;   // 12,582,912 elems
constexpr size_t WSLOT = (size_t)Cn * 256 * 256;     // 1,572,864

typedef __bf16 bf16_t;
typedef bf16_t bf16x8 __attribute__((ext_vector_type(8)));
typedef bf16_t bf16x4 __attribute__((ext_vector_type(4)));
typedef float f32x4 __attribute__((ext_vector_type(4)));

// global -> LDS direct 16B copy (dest = wave-uniform base + lane*16)
__device__ __forceinline__ void gl2lds16(const bf16_t* g, bf16_t* l) {
    typedef const __attribute__((address_space(1))) unsigned int* gp_t;
    typedef __attribute__((address_space(3))) unsigned int* lp_t;
    __builtin_amdgcn_global_load_lds((gp_t)(unsigned long long)g,
                                     (lp_t)(unsigned int)(unsigned long long)l,
                                     16, 0, 0);
}

// ---------------------------------------------------------------------------
// x fp32 -> bf16
// ---------------------------------------------------------------------------
__global__ __launch_bounds__(256) void conv_x_k(const float* __restrict__ x,
                                                bf16_t* __restrict__ xb) {
    const size_t i = ((size_t)blockIdx.x * 256 + threadIdx.x) * 4;
    const float4 v = *(const float4*)(x + i);
    bf16x4 o = {(bf16_t)v.x, (bf16_t)v.y, (bf16_t)v.z, (bf16_t)v.w};
    *(bf16x4*)(xb + i) = o;
}

// ---------------------------------------------------------------------------
// Wq_s copy-convert (source already e-contiguous): [h,c,p,e] -> [c][n=h*32+p][e]
// ---------------------------------------------------------------------------
__global__ __launch_bounds__(256) void conv_w_copy_k(const float* __restrict__ W,
                                                     bf16_t* __restrict__ out) {
    const int row = blockIdx.x * 4 + (threadIdx.x >> 6);   // c*256+n
    const int lane = threadIdx.x & 63;
    const int n = row & 255, c = row >> 8;
    const float* src = W + (size_t)c * (Pn * En) + (size_t)(n >> 5) * (Cn * Pn * En) +
                       (size_t)(n & 31) * En + lane * 4;
    const float4 v = *(const float4*)src;
    bf16x4 o = {(bf16_t)v.x, (bf16_t)v.y, (bf16_t)v.z, (bf16_t)v.w};
    *(bf16x4*)(out + (size_t)row * 256 + lane * 4) = o;
}

// ---------------------------------------------------------------------------
// Transpose-convert for e-strided weights -> canonical [slot][c][n][e].
// ---------------------------------------------------------------------------
struct TDesc { const float* W; int Sc, Snh, Se; };

__global__ __launch_bounds__(256) void conv_w_tr_k(
    TDesc d0, TDesc d1, TDesc d2, TDesc d3, TDesc d4,
    bf16_t* __restrict__ out)
{
    TDesc d;
    switch (blockIdx.z) {
        case 0: d = d0; break; case 1: d = d1; break; case 2: d = d2; break;
        case 3: d = d3; break; default: d = d4; break;
    }
    const int g = blockIdx.x & 7, et = blockIdx.x >> 3;
    const int c = blockIdx.y;

    __shared__ float tile[32][65];

    const int t = threadIdx.x;
    const float* base = d.W + (size_t)c * d.Sc + (size_t)g * d.Snh;

#pragma unroll
    for (int pass = 0; pass < 2; ++pass) {
        const int e_local = pass * 32 + (t >> 3);
        const int j4 = (t & 7) * 4;
        const float4 v = *(const float4*)(base + (size_t)(et * 64 + e_local) * d.Se + j4);
        tile[j4 + 0][e_local] = v.x;
        tile[j4 + 1][e_local] = v.y;
        tile[j4 + 2][e_local] = v.z;
        tile[j4 + 3][e_local] = v.w;
    }
    __syncthreads();

    const int j = t >> 3, e8 = (t & 7) * 8;
    bf16x8 o;
#pragma unroll
    for (int k = 0; k < 8; ++k) o[k] = (bf16_t)tile[j][e8 + k];
    *(bf16x8*)(out + (size_t)blockIdx.z * WSLOT +
               ((size_t)c * 256 + g * 32 + j) * 256 + et * 64 + e8) = o;
}

// small shared spatial k/v weights (tiny: 64 KB each)
__global__ __launch_bounds__(256) void conv_w_k(const float* __restrict__ W,
                                                bf16_t* __restrict__ Wb,
                                                int Sc, int Snh, int Snp, int Se) {
    const int n = blockIdx.x & 255, c = blockIdx.x >> 8;
    const int e = threadIdx.x;
    Wb[(size_t)blockIdx.x * 256 + e] =
        (bf16_t)W[(size_t)c * Sc + (size_t)(n >> 5) * Snh + (n & 31) * Snp + (size_t)e * Se];
}

// ---------------------------------------------------------------------------
// bf16 MFMA GEMM (QKV projections), 3 fused projections sharing A.
// 3-buf counted-vmcnt pipeline + source-side XOR swizzle (see R4 notes).
// trans=0: output n-inner; trans=1: output m-inner.
// ---------------------------------------------------------------------------
struct GDesc { const bf16_t* W; bf16_t* O; int Aoff, Wc, Ob, Oc, Os, Onh, Onp, trans; };

template <int NP>
__global__ __launch_bounds__(256) void gemm_mfma(
    const bf16_t* __restrict__ A, int Ab, int Ac, int As,
    GDesc g0, GDesc g1, GDesc g2)
{
    const int b = blockIdx.x, c = blockIdx.z;
    const int proj = (NP == 1) ? 0 : ((int)blockIdx.y >> 1);
    const int nt = (NP == 1) ? (int)blockIdx.y : ((int)blockIdx.y & 1);
    GDesc g = (proj == 0) ? g0 : (proj == 1) ? g1 : g2;

    __shared__ bf16_t smem[3][2][128 * 32];   // 48 KB
    bf16_t* Cs = &smem[0][0][0];              // epilogue staging (aliased)

    const int tid = threadIdx.x, wv = tid >> 6, ln = tid & 63;
    const int wm = (wv >> 1) * 64, wn = (wv & 1) * 64;
    const int lr = ln & 15, hi = ln >> 4;

    const bf16_t* Abase = A + g.Aoff + (size_t)b * Ab + (size_t)c * Ac;
    const bf16_t* Bbase = g.W + (size_t)c * g.Wc + (size_t)(nt * 128) * 256;

    auto stage = [&](int buf, int kt) {
        const int k0 = kt * 32;
#pragma unroll
        for (int it = 0; it < 2; ++it) {
            const int cb = it * 256 + wv * 64;
            const int mc = cb + ln;
            const int row = mc >> 2;
            const int kc = (((mc & 3) ^ ((row >> 1) & 3)) * 8);
            gl2lds16(Abase + (size_t)row * As + k0 + kc, &smem[buf][0][cb * 8]);
            gl2lds16(Bbase + (size_t)row * 256 + k0 + kc, &smem[buf][1][cb * 8]);
        }
    };

    f32x4 acc[4][4] = {};

    stage(0, 0);
    stage(1, 1);

#pragma unroll
    for (int kt = 0; kt < 8; ++kt) {
        if (kt < 6) stage((kt + 2) % 3, kt + 2);
        if (kt < 6)       asm volatile("s_waitcnt vmcnt(8)" ::: "memory");
        else if (kt == 6) asm volatile("s_waitcnt vmcnt(4)" ::: "memory");
        else              asm volatile("s_waitcnt vmcnt(0)" ::: "memory");
        __builtin_amdgcn_s_barrier();
        __builtin_amdgcn_sched_barrier(0);

        const int cur = kt % 3;
        bf16x8 af[4], bfr[4];
#pragma unroll
        for (int i = 0; i < 4; ++i) {
            const int r = wm + i * 16 + lr;
            af[i] = *(const bf16x8*)&smem[cur][0][r * 32 + ((hi ^ ((r >> 1) & 3)) * 8)];
        }
#pragma unroll
        for (int j = 0; j < 4; ++j) {
            const int r = wn + j * 16 + lr;
            bfr[j] = *(const bf16x8*)&smem[cur][1][r * 32 + ((hi ^ ((r >> 1) & 3)) * 8)];
        }
        __builtin_amdgcn_s_setprio(1);
#pragma unroll
        for (int i = 0; i < 4; ++i)
#pragma unroll
            for (int j = 0; j < 4; ++j)
                acc[i][j] = __builtin_amdgcn_mfma_f32_16x16x32_bf16(af[i], bfr[j], acc[i][j], 0, 0, 0);
        __builtin_amdgcn_s_setprio(0);

        __builtin_amdgcn_sched_barrier(0);
        __builtin_amdgcn_s_barrier();
    }

#pragma unroll
    for (int pass = 0; pass < 2; ++pass) {
        if (!g.trans) {
            if (wm == pass * 64) {
#pragma unroll
                for (int i = 0; i < 4; ++i)
#pragma unroll
                    for (int j = 0; j < 4; ++j)
#pragma unroll
                        for (int r = 0; r < 4; ++r)
                            Cs[(i * 16 + hi * 4 + r) * 136 + wn + j * 16 + lr] =
                                (bf16_t)acc[i][j][r];
            }
            __syncthreads();
#pragma unroll
            for (int it = 0; it < 2; ++it) {
                const int lrow = it * 32 + (tid >> 3);
                const int n0 = (tid & 7) * 16;
                bf16x8 v0 = *(const bf16x8*)&Cs[lrow * 136 + n0];
                bf16x8 v1 = *(const bf16x8*)&Cs[lrow * 136 + n0 + 8];
                const int m = pass * 64 + lrow;
                const int n = nt * 128 + n0;
                bf16_t* dst = g.O + (size_t)b * g.Ob + (size_t)c * g.Oc +
                              (size_t)m * g.Os + (size_t)(n >> 5) * g.Onh + (n & 31);
                *(bf16x8*)dst = v0;
                *(bf16x8*)(dst + 8) = v1;
            }
            __syncthreads();
        } else {
            if (wn == pass * 64) {
#pragma unroll
                for (int i = 0; i < 4; ++i)
#pragma unroll
                    for (int j = 0; j < 4; ++j) {
                        bf16x4 pk = {(bf16_t)acc[i][j][0], (bf16_t)acc[i][j][1],
                                     (bf16_t)acc[i][j][2], (bf16_t)acc[i][j][3]};
                        *(bf16x4*)&Cs[(j * 16 + lr) * 136 + wm + i * 16 + hi * 4] = pk;
                    }
            }
            __syncthreads();
#pragma unroll
            for (int it = 0; it < 2; ++it) {
                const int lrow = it * 32 + (tid >> 3);
                const int m0 = (tid & 7) * 16;
                bf16x8 v0 = *(const bf16x8*)&Cs[lrow * 136 + m0];
                bf16x8 v1 = *(const bf16x8*)&Cs[lrow * 136 + m0 + 8];
                const int n = nt * 128 + pass * 64 + lrow;
                bf16_t* dst = g.O + (size_t)b * g.Ob + (size_t)c * g.Oc +
                              (size_t)(n >> 5) * g.Onh + (size_t)(n & 31) * g.Onp + m0;
                *(bf16x8*)dst = v0;
                *(bf16x8*)(dst + 8) = v1;
            }
            __syncthreads();
        }
    }
}

// ---------------------------------------------------------------------------
// Fused: AO = LN(x + attnS*Wo_s) + LN(x + attnT*Wo_t)        [wo_ln_fused]
// Block = 64 rows x 256 cols; 4 waves = 4 n-slices; two 8-step K-loops
// (2-buf counted-vmcnt(5), XOR-swizzled); results staged to LDS; row-parallel
// LN pass (4 threads/row, 2 shuffles) writes AO only.
// LDS: stage bufs [0,20480) (2 x {A 2048 el, B 8192 el}); Ss [0,16896),
// Ts [16896,33792) (aliased after loops). 67.6 KB -> 2 blocks/CU.
// ---------------------------------------------------------------------------
__global__ __launch_bounds__(256) void wo_ln_fused(
    const bf16_t* __restrict__ A1, const bf16_t* __restrict__ A2,
    const bf16_t* __restrict__ W1, const bf16_t* __restrict__ W2,
    const bf16_t* __restrict__ xb, const float* __restrict__ g,
    const float* __restrict__ beta, bf16_t* __restrict__ AO)
{
    const int bx = blockIdx.x, c = blockIdx.z;
    const int R = ((bx >> 1) * Cn + c) * Sn + (bx & 1) * 64;

    __shared__ bf16_t lds[33792];

    const int tid = threadIdx.x, wv = tid >> 6, ln = tid & 63;
    const int wn = wv * 64, lr = ln & 15, hi = ln >> 4;

    const bf16_t* Ab0 = A1 + (size_t)R * 256;
    const bf16_t* Ab1 = A2 + (size_t)R * 256;
    const bf16_t* Wb0 = W1 + (size_t)c * 65536;
    const bf16_t* Wb1 = W2 + (size_t)c * 65536;

    auto stage = [&](int buf, int t) {
        const bf16_t* Asrc = (t < 8) ? Ab0 : Ab1;
        const bf16_t* Wsrc = (t < 8) ? Wb0 : Wb1;
        const int k0 = (t & 7) * 32;
        bf16_t* base = &lds[buf * 10240];
        {
            const int ch = wv * 64 + ln;            // A: 256 chunks
            const int row = ch >> 2;
            const int kc = (((ch & 3) ^ ((row >> 1) & 3)) * 8);
            gl2lds16(Asrc + (size_t)row * 256 + k0 + kc, base + ch * 8);
        }
#pragma unroll
        for (int g2 = 0; g2 < 4; ++g2) {            // B: 1024 chunks
            const int ch = g2 * 256 + wv * 64 + ln;
            const int row = ch >> 2;
            const int kc = (((ch & 3) ^ ((row >> 1) & 3)) * 8);
            gl2lds16(Wsrc + (size_t)row * 256 + k0 + kc, base + 2048 + ch * 8);
        }
    };

    f32x4 accS[4][4] = {}, accT[4][4] = {};

    stage(0, 0);
#pragma unroll
    for (int t = 0; t < 16; ++t) {
        if (t < 15) {
            stage((t + 1) & 1, t + 1);
            asm volatile("s_waitcnt vmcnt(5)" ::: "memory");
        } else {
            asm volatile("s_waitcnt vmcnt(0)" ::: "memory");
        }
        __builtin_amdgcn_s_barrier();
        __builtin_amdgcn_sched_barrier(0);

        const bf16_t* base = &lds[(t & 1) * 10240];
        bf16x8 af[4], bfr[4];
#pragma unroll
        for (int i = 0; i < 4; ++i) {
            const int r = i * 16 + lr;
            af[i] = *(const bf16x8*)(base + r * 32 + ((hi ^ ((r >> 1) & 3)) * 8));
        }
#pragma unroll
        for (int j = 0; j < 4; ++j) {
            const int r = wn + j * 16 + lr;
            bfr[j] = *(const bf16x8*)(base + 2048 + r * 32 + ((hi ^ ((r >> 1) & 3)) * 8));
        }
        __builtin_amdgcn_s_setprio(1);
        if (t < 8) {
#pragma unroll
            for (int i = 0; i < 4; ++i)
#pragma unroll
                for (int j = 0; j < 4; ++j)
                    accS[i][j] = __builtin_amdgcn_mfma_f32_16x16x32_bf16(af[i], bfr[j], accS[i][j], 0, 0, 0);
        } else {
#pragma unroll
            for (int i = 0; i < 4; ++i)
#pragma unroll
                for (int j = 0; j < 4; ++j)
                    accT[i][j] = __builtin_amdgcn_mfma_f32_16x16x32_bf16(af[i], bfr[j], accT[i][j], 0, 0, 0);
        }
        __builtin_amdgcn_s_setprio(0);
        __builtin_amdgcn_sched_barrier(0);
        __builtin_amdgcn_s_barrier();
    }

    // stage results (stage bufs dead)
    bf16_t* Ss = &lds[0];
    bf16_t* Ts = &lds[16896];
#pragma unroll
    for (int i = 0; i < 4; ++i)
#pragma unroll
        for (int j = 0; j < 4; ++j)
#pragma unroll
            for (int r = 0; r < 4; ++r) {
                const int m = i * 16 + hi * 4 + r;
                const int n = wn + j * 16 + lr;
                Ss[m * 264 + n] = (bf16_t)accS[i][j][r];
                Ts[m * 264 + n] = (bf16_t)accT[i][j][r];
            }
    __syncthreads();

    // row-parallel LN pass: 4 threads per row, 64 cols each
    const int row = tid >> 2, c0 = (tid & 3) * 64;
    const bf16_t* xp = xb + (size_t)(R + row) * 256 + c0;
    bf16x8 xv[8];
    float s1 = 0, q1 = 0, s2 = 0, q2 = 0;
#pragma unroll
    for (int u = 0; u < 8; ++u) {
        xv[u] = *(const bf16x8*)(xp + u * 8);
        bf16x8 sv = *(const bf16x8*)&Ss[row * 264 + c0 + u * 8];
        bf16x8 tv = *(const bf16x8*)&Ts[row * 264 + c0 + u * 8];
#pragma unroll
        for (int e = 0; e < 8; ++e) {
            const float xf = (float)xv[u][e];
            const float a = xf + (float)sv[e];
            const float t2 = xf + (float)tv[e];
            s1 += a; q1 += a * a; s2 += t2; q2 += t2 * t2;
        }
    }
    s1 += __shfl_xor(s1, 1); s1 += __shfl_xor(s1, 2);
    q1 += __shfl_xor(q1, 1); q1 += __shfl_xor(q1, 2);
    s2 += __shfl_xor(s2, 1); s2 += __shfl_xor(s2, 2);
    q2 += __shfl_xor(q2, 1); q2 += __shfl_xor(q2, 2);
    const float mu1 = s1 / 256.f, mu2 = s2 / 256.f;
    const float r1 = rsqrtf(q1 / 256.f - mu1 * mu1 + 1e-6f);
    const float r2 = rsqrtf(q2 / 256.f - mu2 * mu2 + 1e-6f);
#pragma unroll
    for (int u = 0; u < 8; ++u) {
        bf16x8 sv = *(const bf16x8*)&Ss[row * 264 + c0 + u * 8];
        bf16x8 tv = *(const bf16x8*)&Ts[row * 264 + c0 + u * 8];
        bf16x8 o8;
#pragma unroll
        for (int e = 0; e < 8; ++e) {
            const int n = c0 + u * 8 + e;
            const float xf = (float)xv[u][e];
            const float a = xf + (float)sv[e];
            const float t2 = xf + (float)tv[e];
            o8[e] = (bf16_t)((a - mu1) * r1 * g[n] + (t2 - mu2) * r2 * g[n] + 2.f * beta[n]);
        }
        *(bf16x8*)(AO + (size_t)(R + row) * 256 + c0 + u * 8) = o8;
    }
}

// ---------------------------------------------------------------------------
// Fused: out = LN(AO + (relu(AO*W1+b1))*W2+b2)               [ff_ln_fused]
// Loop1: A=AO (staged), W=W1 -> h = relu(.+b1) -> Hs LDS [64][264].
// Loop2: A-fragments read directly from Hs (no staging), W=W2 -> Fs (+b2).
// Row-parallel LN(AO+Fs) writes final f32 output.
// LDS: stage [0,20480); Hs [20480,37376); Fs aliases [0,16896). 74.8 KB.
// ---------------------------------------------------------------------------
__global__ __launch_bounds__(256) void ff_ln_fused(
    const bf16_t* __restrict__ AO, const bf16_t* __restrict__ W1,
    const bf16_t* __restrict__ W2, const float* __restrict__ b1v,
    const float* __restrict__ b2v, const float* __restrict__ g,
    const float* __restrict__ beta, float* __restrict__ out)
{
    const int bx = blockIdx.x, c = blockIdx.z;
    const int R = ((bx >> 1) * Cn + c) * Sn + (bx & 1) * 64;

    __shared__ bf16_t lds[37376];

    const int tid = threadIdx.x, wv = tid >> 6, ln = tid & 63;
    const int wn = wv * 64, lr = ln & 15, hi = ln >> 4;

    const bf16_t* Abase = AO + (size_t)R * 256;
    const bf16_t* W1b = W1 + (size_t)c * 65536;
    const bf16_t* W2b = W2 + (size_t)c * 65536;
    bf16_t* Hs = &lds[20480];

    auto stageA = [&](int buf, int kt) {
        const int k0 = kt * 32;
        const int ch = wv * 64 + ln;
        const int row = ch >> 2;
        const int kc = (((ch & 3) ^ ((row >> 1) & 3)) * 8);
        gl2lds16(Abase + (size_t)row * 256 + k0 + kc, &lds[buf * 10240] + ch * 8);
    };
    auto stageB = [&](int buf, int kt, const bf16_t* Wsrc) {
        const int k0 = kt * 32;
#pragma unroll
        for (int g2 = 0; g2 < 4; ++g2) {
            const int ch = g2 * 256 + wv * 64 + ln;
            const int row = ch >> 2;
            const int kc = (((ch & 3) ^ ((row >> 1) & 3)) * 8);
            gl2lds16(Wsrc + (size_t)row * 256 + k0 + kc, &lds[buf * 10240] + 2048 + ch * 8);
        }
    };

    f32x4 acc[4][4] = {};

    // ---- loop 1: h = AO * W1 ----
    stageA(0, 0); stageB(0, 0, W1b);
#pragma unroll
    for (int t = 0; t < 8; ++t) {
        if (t < 7) {
            stageA((t + 1) & 1, t + 1); stageB((t + 1) & 1, t + 1, W1b);
            asm volatile("s_waitcnt vmcnt(5)" ::: "memory");
        } else {
            asm volatile("s_waitcnt vmcnt(0)" ::: "memory");
        }
        __builtin_amdgcn_s_barrier();
        __builtin_amdgcn_sched_barrier(0);
        const bf16_t* base = &lds[(t & 1) * 10240];
        bf16x8 af[4], bfr[4];
#pragma unroll
        for (int i = 0; i < 4; ++i) {
            const int r = i * 16 + lr;
            af[i] = *(const bf16x8*)(base + r * 32 + ((hi ^ ((r >> 1) & 3)) * 8));
        }
#pragma unroll
        for (int j = 0; j < 4; ++j) {
            const int r = wn + j * 16 + lr;
            bfr[j] = *(const bf16x8*)(base + 2048 + r * 32 + ((hi ^ ((r >> 1) & 3)) * 8));
        }
        __builtin_amdgcn_s_setprio(1);
#pragma unroll
        for (int i = 0; i < 4; ++i)
#pragma unroll
            for (int j = 0; j < 4; ++j)
                acc[i][j] = __builtin_amdgcn_mfma_f32_16x16x32_bf16(af[i], bfr[j], acc[i][j], 0, 0, 0);
        __builtin_amdgcn_s_setprio(0);
        __builtin_amdgcn_sched_barrier(0);
        __builtin_amdgcn_s_barrier();
    }

    // interlude: issue first W2 tile, write h (bias+relu), sync
    stageB(0, 0, W2b);
#pragma unroll
    for (int i = 0; i < 4; ++i)
#pragma unroll
        for (int j = 0; j < 4; ++j) {
            const int n = wn + j * 16 + lr;
            const float bv = b1v[c * 256 + n];
#pragma unroll
            for (int r = 0; r < 4; ++r)
                Hs[(i * 16 + hi * 4 + r) * 264 + n] =
                    (bf16_t)fmaxf(acc[i][j][r] + bv, 0.f);
        }
    __syncthreads();

    // ---- loop 2: ff = h * W2 (A-fragments straight from Hs) ----
    f32x4 acc2[4][4] = {};
#pragma unroll
    for (int t = 0; t < 8; ++t) {
        if (t < 7) {
            stageB((t + 1) & 1, t + 1, W2b);
            asm volatile("s_waitcnt vmcnt(4)" ::: "memory");
        } else {
            asm volatile("s_waitcnt vmcnt(0)" ::: "memory");
        }
        __builtin_amdgcn_s_barrier();
        __builtin_amdgcn_sched_barrier(0);
        const bf16_t* base = &lds[(t & 1) * 10240];
        bf16x8 af[4], bfr[4];
#pragma unroll
        for (int i = 0; i < 4; ++i)
            af[i] = *(const bf16x8*)&Hs[(i * 16 + lr) * 264 + t * 32 + hi * 8];
#pragma unroll
        for (int j = 0; j < 4; ++j) {
            const int r = wn + j * 16 + lr;
            bfr[j] = *(const bf16x8*)(base + 2048 + r * 32 + ((hi ^ ((r >> 1) & 3)) * 8));
        }
        __builtin_amdgcn_s_setprio(1);
#pragma unroll
        for (int i = 0; i < 4; ++i)
#pragma unroll
            for (int j = 0; j < 4; ++j)
                acc2[i][j] = __builtin_amdgcn_mfma_f32_16x16x32_bf16(af[i], bfr[j], acc2[i][j], 0, 0, 0);
        __builtin_amdgcn_s_setprio(0);
        __builtin_amdgcn_sched_barrier(0);
        __builtin_amdgcn_s_barrier();
    }

    // stage ff (+bias2)
    bf16_t* Fs = &lds[0];
#pragma unroll
    for (int i = 0; i < 4; ++i)
#pragma unroll
        for (int j = 0; j < 4; ++j) {
            const int n = wn + j * 16 + lr;
            const float bv = b2v[c * 256 + n];
#pragma unroll
            for (int r = 0; r < 4; ++r)
                Fs[(i * 16 + hi * 4 + r) * 264 + n] = (bf16_t)(acc2[i][j][r] + bv);
        }
    __syncthreads();

    // row-parallel LN(AO + ff) -> f32 out
    const int row = tid >> 2, c0 = (tid & 3) * 64;
    const bf16_t* ap = AO + (size_t)(R + row) * 256 + c0;
    bf16x8 av[8];
    float s = 0, q = 0;
#pragma unroll
    for (int u = 0; u < 8; ++u) {
        av[u] = *(const bf16x8*)(ap + u * 8);
        bf16x8 fv = *(const bf16x8*)&Fs[row * 264 + c0 + u * 8];
#pragma unroll
        for (int e = 0; e < 8; ++e) {
            const float a = (float)av[u][e] + (float)fv[e];
            s += a; q += a * a;
        }
    }
    s += __shfl_xor(s, 1); s += __shfl_xor(s, 2);
    q += __shfl_xor(q, 1); q += __shfl_xor(q, 2);
    const float mu = s / 256.f;
    const float rin = rsqrtf(q / 256.f - mu * mu + 1e-6f);
#pragma unroll
    for (int u = 0; u < 8; ++u) {
        bf16x8 fv = *(const bf16x8*)&Fs[row * 264 + c0 + u * 8];
        float4 o0, o1;
        float* op = &o0.x;
#pragma unroll
        for (int e = 0; e < 8; ++e) {
            const int n = c0 + u * 8 + e;
            const float a = (float)av[u][e] + (float)fv[e];
            const float v = (a - mu) * rin * g[n] + beta[n];
            if (e < 4) (&o0.x)[e] = v; else (&o1.x)[e - 4] = v;
        }
        (void)op;
        float* dst = out + (size_t)(R + row) * 256 + c0 + u * 8;
        *(float4*)dst = o0;
        *(float4*)(dst + 4) = o1;
    }
}

// ---------------------------------------------------------------------------
// Spatial attention, MFMA, one wave per (b,s,h). 24x24 padded to 32.
// ---------------------------------------------------------------------------
__global__ __launch_bounds__(256) void attn_spatial_mfma(
    const bf16_t* __restrict__ Q, const bf16_t* __restrict__ K,
    const bf16_t* __restrict__ V, bf16_t* __restrict__ O)
{
    __shared__ bf16_t Ps[4][32 * 40];
    __shared__ bf16_t Vt[4][32 * 40];

    const int tid = threadIdx.x, wv = tid >> 6, ln = tid & 63;
    const int lr = ln & 15, hi = ln >> 4, lk = hi * 8;

    const int bsh = blockIdx.x * 4 + wv;
    const int h = bsh & 7, s = (bsh >> 3) & 127, b = bsh >> 10;
    const size_t qb = (size_t)bsh * (Cn * Pn);

    {
        const int p = ln >> 1, c0 = 24 + (ln & 1) * 4;
        bf16x4 z = {};
        *(bf16x4*)&Vt[wv][p * 40 + c0] = z;
    }
#pragma unroll
    for (int it = 0; it < 2; ++it) {
        const int ch = it * 64 + ln;
        if (ch < 96) {
            const int cc = ch >> 2, p0 = (ch & 3) * 8;
            bf16x8 v = *(const bf16x8*)(V + qb + cc * 32 + p0);
#pragma unroll
            for (int j = 0; j < 8; ++j)
                Vt[wv][(p0 + j) * 40 + cc] = v[j];
        }
    }

    bf16x8 aq0 = *(const bf16x8*)(Q + qb + lr * 32 + lk);
    bf16x8 aq1 = *(const bf16x8*)(Q + qb + (16 + lr) * 32 + lk);
    bf16x8 bk0 = *(const bf16x8*)(K + qb + lr * 32 + lk);
    bf16x8 bk1 = *(const bf16x8*)(K + qb + (16 + lr) * 32 + lk);
    const f32x4 zz = {0.f, 0.f, 0.f, 0.f};
    f32x4 sc[2][2];
    sc[0][0] = __builtin_amdgcn_mfma_f32_16x16x32_bf16(aq0, bk0, zz, 0, 0, 0);
    sc[0][1] = __builtin_amdgcn_mfma_f32_16x16x32_bf16(aq0, bk1, zz, 0, 0, 0);
    sc[1][0] = __builtin_amdgcn_mfma_f32_16x16x32_bf16(aq1, bk0, zz, 0, 0, 0);
    sc[1][1] = __builtin_amdgcn_mfma_f32_16x16x32_bf16(aq1, bk1, zz, 0, 0, 0);

    const float scale = 0.17677669529663687f;
#pragma unroll
    for (int i = 0; i < 2; ++i) {
        float s0[4], s1[4], mx[4];
#pragma unroll
        for (int r = 0; r < 4; ++r) {
            s0[r] = sc[i][0][r] * scale;
            s1[r] = (lr >= 8) ? -3.0e38f : sc[i][1][r] * scale;
            mx[r] = fmaxf(s0[r], s1[r]);
        }
#pragma unroll
        for (int d = 1; d < 16; d <<= 1)
#pragma unroll
            for (int r = 0; r < 4; ++r) mx[r] = fmaxf(mx[r], __shfl_xor(mx[r], d));
        float e0[4], e1[4], sm[4];
#pragma unroll
        for (int r = 0; r < 4; ++r) {
            e0[r] = __expf(s0[r] - mx[r]);
            e1[r] = __expf(s1[r] - mx[r]);
            sm[r] = e0[r] + e1[r];
        }
#pragma unroll
        for (int d = 1; d < 16; d <<= 1)
#pragma unroll
            for (int r = 0; r < 4; ++r) sm[r] += __shfl_xor(sm[r], d);
#pragma unroll
        for (int r = 0; r < 4; ++r) {
            const float inv = 1.f / sm[r];
            const int row = i * 16 + hi * 4 + r;
            Ps[wv][row * 40 + lr]      = (bf16_t)(e0[r] * inv);
            Ps[wv][row * 40 + 16 + lr] = (bf16_t)(e1[r] * inv);
        }
    }

    bf16x8 ap0 = *(const bf16x8*)&Ps[wv][lr * 40 + lk];
    bf16x8 ap1 = *(const bf16x8*)&Ps[wv][(16 + lr) * 40 + lk];
    bf16x8 bv0 = *(const bf16x8*)&Vt[wv][lr * 40 + lk];
    bf16x8 bv1 = *(const bf16x8*)&Vt[wv][(16 + lr) * 40 + lk];
    f32x4 o[2][2];
    o[0][0] = __builtin_amdgcn_mfma_f32_16x16x32_bf16(ap0, bv0, zz, 0, 0, 0);
    o[0][1] = __builtin_amdgcn_mfma_f32_16x16x32_bf16(ap0, bv1, zz, 0, 0, 0);
    o[1][0] = __builtin_amdgcn_mfma_f32_16x16x32_bf16(ap1, bv0, zz, 0, 0, 0);
    o[1][1] = __builtin_amdgcn_mfma_f32_16x16x32_bf16(ap1, bv1, zz, 0, 0, 0);

#pragma unroll
    for (int i = 0; i < 2; ++i)
#pragma unroll
        for (int r = 0; r < 4; ++r) {
            const int c = i * 16 + hi * 4 + r;
            if (c < 24) {
                const size_t ob = ((size_t)(b * Cn + c) * Sn + s) * En + h * Pn;
#pragma unroll
                for (int j = 0; j < 2; ++j)
                    O[ob + j * 16 + lr] = (bf16_t)o[i][j][r];
            }
        }
}

// ---------------------------------------------------------------------------
// Temporal attention, MFMA. One block (4 waves) per (b,h,c).
// ---------------------------------------------------------------------------
__global__ __launch_bounds__(256) void attn_temporal_mfma(
    const bf16_t* __restrict__ Q, const bf16_t* __restrict__ K,
    const bf16_t* __restrict__ Vt, bf16_t* __restrict__ O)
{
    const int c = blockIdx.x, h = blockIdx.y, b = blockIdx.z;
    const size_t base = ((size_t)(b * Hn + h) * Cn + c) * (Sn * Pn);

    __shared__ bf16_t Qs[128 * 32];
    __shared__ bf16_t Ks[128 * 32];
    __shared__ bf16_t Vs[32 * 136];
    __shared__ bf16_t Ps[128 * 136];

    const int tid = threadIdx.x, wv = tid >> 6, ln = tid & 63;
    const int lr = ln & 15, lk = (ln >> 4) * 8;

#pragma unroll
    for (int it = 0; it < 2; ++it) {
        const int cb = it * 256 + wv * 64;
        const int mc = cb + ln;
        const int row = mc >> 2, kc = (mc & 3) * 8;
        gl2lds16(Q + base + row * 32 + kc, &Qs[cb * 8]);
        gl2lds16(K + base + row * 32 + kc, &Ks[cb * 8]);
    }
#pragma unroll
    for (int it = 0; it < 2; ++it) {
        const int mc = it * 256 + tid;
        const int p = mc >> 4, scn = (mc & 15) * 8;
        bf16x8 v = *(const bf16x8*)(Vt + base + p * 128 + scn);
        *(bf16x8*)&Vs[p * 136 + scn] = v;
    }
    __syncthreads();

    const int r0 = wv * 32;
    bf16x8 aq0 = *(const bf16x8*)&Qs[(r0 + lr) * 32 + lk];
    bf16x8 aq1 = *(const bf16x8*)&Qs[(r0 + 16 + lr) * 32 + lk];
    f32x4 sc_[2][8];
    const f32x4 zz = {0.f, 0.f, 0.f, 0.f};
#pragma unroll
    for (int j = 0; j < 8; ++j) {
        bf16x8 bk = *(const bf16x8*)&Ks[(j * 16 + lr) * 32 + lk];
        sc_[0][j] = __builtin_amdgcn_mfma_f32_16x16x32_bf16(aq0, bk, zz, 0, 0, 0);
        sc_[1][j] = __builtin_amdgcn_mfma_f32_16x16x32_bf16(aq1, bk, zz, 0, 0, 0);
    }

    const float scale = 0.17677669529663687f;
#pragma unroll
    for (int i = 0; i < 2; ++i) {
        float mx[4], sm[4];
#pragma unroll
        for (int r = 0; r < 4; ++r) {
            float m = sc_[i][0][r];
#pragma unroll
            for (int j = 1; j < 8; ++j) m = fmaxf(m, sc_[i][j][r]);
            mx[r] = m;
        }
#pragma unroll
        for (int d = 1; d < 16; d <<= 1)
#pragma unroll
            for (int r = 0; r < 4; ++r) mx[r] = fmaxf(mx[r], __shfl_xor(mx[r], d));
#pragma unroll
        for (int r = 0; r < 4; ++r) sm[r] = 0.f;
#pragma unroll
        for (int j = 0; j < 8; ++j)
#pragma unroll
            for (int r = 0; r < 4; ++r) {
                const float e = __expf((sc_[i][j][r] - mx[r]) * scale);
                sc_[i][j][r] = e; sm[r] += e;
            }
#pragma unroll
        for (int d = 1; d < 16; d <<= 1)
#pragma unroll
            for (int r = 0; r < 4; ++r) sm[r] += __shfl_xor(sm[r], d);
        float inv[4];
#pragma unroll
        for (int r = 0; r < 4; ++r) inv[r] = 1.f / sm[r];
        const int rb = r0 + i * 16 + (ln >> 4) * 4;
#pragma unroll
        for (int j = 0; j < 8; ++j)
#pragma unroll
            for (int r = 0; r < 4; ++r)
                Ps[(rb + r) * 136 + j * 16 + lr] = (bf16_t)(sc_[i][j][r] * inv[r]);
    }
    __syncthreads();

    f32x4 o[2][2] = {};
#pragma unroll
    for (int kk = 0; kk < 4; ++kk) {
        bf16x8 ap0 = *(const bf16x8*)&Ps[(r0 + lr) * 136 + kk * 32 + lk];
        bf16x8 ap1 = *(const bf16x8*)&Ps[(r0 + 16 + lr) * 136 + kk * 32 + lk];
        bf16x8 bv0 = *(const bf16x8*)&Vs[lr * 136 + kk * 32 + lk];
        bf16x8 bv1 = *(const bf16x8*)&Vs[(16 + lr) * 136 + kk * 32 + lk];
        o[0][0] = __builtin_amdgcn_mfma_f32_16x16x32_bf16(ap0, bv0, o[0][0], 0, 0, 0);
        o[0][1] = __builtin_amdgcn_mfma_f32_16x16x32_bf16(ap0, bv1, o[0][1], 0, 0, 0);
        o[1][0] = __builtin_amdgcn_mfma_f32_16x16x32_bf16(ap1, bv0, o[1][0], 0, 0, 0);
        o[1][1] = __builtin_amdgcn_mfma_f32_16x16x32_bf16(ap1, bv1, o[1][1], 0, 0, 0);
    }

#pragma unroll
    for (int i = 0; i < 2; ++i) {
        const int sb = r0 + i * 16 + (ln >> 4) * 4;
#pragma unroll
        for (int j = 0; j < 2; ++j) {
            const int p = h * 32 + j * 16 + lr;
#pragma unroll
            for (int r = 0; r < 4; ++r)
                O[((size_t)(b * Cn + c) * Sn + (sb + r)) * En + p] = (bf16_t)o[i][j][r];
        }
    }
}

// ---------------------------------------------------------------------------
extern "C" void kernel_launch(void* const* d_in, const int* in_sizes, int n_in,
                              void* d_out, int out_size, void* d_ws, size_t ws_size,
                              hipStream_t stream)
{
    const float* x     = (const float*)d_in[0];
    const float* Wq_s  = (const float*)d_in[1];
    const float* Wk_s  = (const float*)d_in[2];
    const float* Wv_s  = (const float*)d_in[3];
    const float* Wo_s  = (const float*)d_in[4];
    const float* Wq_t  = (const float*)d_in[5];
    const float* Wk_t  = (const float*)d_in[6];
    const float* Wv_t  = (const float*)d_in[7];
    const float* Wo_t  = (const float*)d_in[8];
    const float* ln_g  = (const float*)d_in[9];
    const float* ln_b  = (const float*)d_in[10];
    const float* ff_w1 = (const float*)d_in[11];
    const float* ff_b1 = (const float*)d_in[12];
    const float* ff_w2 = (const float*)d_in[13];
    const float* ff_b2 = (const float*)d_in[14];
    float* out = (float*)d_out;

    bf16_t* wsb = (bf16_t*)d_ws;
    bf16_t* b0 = wsb;
    bf16_t* b1 = wsb + NBUF;
    bf16_t* b2 = wsb + 2 * NBUF;
    bf16_t* b3 = wsb + 3 * NBUF;
    bf16_t* b4 = wsb + 4 * NBUF;

    // d_out doubles as scratch: xb + weight slots (consumed before out write)
    bf16_t* xb = (bf16_t*)d_out;
    bf16_t* wb = xb + NBUF;
    bf16_t* w_qs = wb + 0 * WSLOT;      // copy-convert slot
    bf16_t* wtr  = wb + 1 * WSLOT;      // 5 transpose slots
    bf16_t* w_os = wtr + 0 * WSLOT;
    bf16_t* w_qt = wtr + 1 * WSLOT;
    bf16_t* w_kt = wtr + 2 * WSLOT;
    bf16_t* w_vt = wtr + 3 * WSLOT;
    bf16_t* w_ot = wtr + 4 * WSLOT;
    bf16_t* w_ks = b4 + NBUF - 2 * 65536;   // consumed by spatial QKV before b4 written
    bf16_t* w_vs = b4 + NBUF - 65536;
    // ff weights converted LATE into b0 (free after attn_temporal reads Q);
    // needed because the f32 out write overlaps the d_out weight slots.
    bf16_t* w_f1 = b0;
    bf16_t* w_f2 = b0 + WSLOT;

    // strides
    const int XAb = Cn * Sn * En, XAc = Sn * En, XAs = En;                          // [B,C,S,E]
    const int QSb = Sn * Hn * Cn * Pn, QSs = Hn * Cn * Pn, QSh = Cn * Pn;           // [B,S,H,C,P]
    const int QTb = Hn * Cn * Sn * Pn, QTh = Cn * Sn * Pn, QTc = Sn * Pn, QTs = Pn; // [B,H,C,S,P]
    const int WCP = 256 * 256;

    // --- conversions (source-major, coalesced) ---
    conv_x_k<<<NBUF / 1024, 256, 0, stream>>>(x, xb);
    conv_w_copy_k<<<1536, 256, 0, stream>>>(Wq_s, w_qs);
    conv_w_tr_k<<<dim3(32, 24, 5), 256, 0, stream>>>(
        TDesc{Wo_s, En * En, Pn, En},                 // [c,e,f]: g=f>>5
        TDesc{Wq_t, En * Pn, Cn * En * Pn, Pn},       // [h,c,e,p]: g=h
        TDesc{Wk_t, En * Pn, Cn * En * Pn, Pn},
        TDesc{Wv_t, En * Pn, Cn * En * Pn, Pn},
        TDesc{Wo_t, En * En, Pn, En},
        wtr);
    conv_w_k<<<256, 256, 0, stream>>>(Wk_s, w_ks, 0, En * Pn, 1, Pn);
    conv_w_k<<<256, 256, 0, stream>>>(Wv_s, w_vs, 0, En * Pn, 1, Pn);

    // --- spatial branch QKV + attention -> b3 ---
    gemm_mfma<3><<<dim3(16, 6, 24), 256, 0, stream>>>(
        xb, XAb, XAc, XAs,
        GDesc{w_qs, b0, 0, WCP, QSb, Pn, QSs, QSh, 1, 0},
        GDesc{w_ks, b1, 0, 0,   QSb, Pn, QSs, QSh, 1, 0},
        GDesc{w_vs, b2, 0, 0,   QSb, Pn, QSs, QSh, 1, 0});
    attn_spatial_mfma<<<Bn * Sn * Hn / 4, 256, 0, stream>>>(b0, b1, b2, b3);

    // --- temporal branch QKV + attention -> b4 ---
    gemm_mfma<3><<<dim3(16, 6, 24), 256, 0, stream>>>(
        xb, XAb, XAc, XAs,
        GDesc{w_qt, b0, 0, WCP, QTb, QTc, QTs, QTh, 1, 0},
        GDesc{w_kt, b1, 0, WCP, QTb, QTc, QTs, QTh, 1, 0},
        GDesc{w_vt, b2, 0, WCP, QTb, QTc, 1, QTh, Sn, 1});
    attn_temporal_mfma<<<dim3(24, 8, 16), 256, 0, stream>>>(b0, b1, b2, b4);

    // --- late conversion of FF weights into b0 (b0 free after attn_temporal) ---
    conv_w_tr_k<<<dim3(32, 24, 2), 256, 0, stream>>>(
        TDesc{ff_w1, En * En, Pn, En},
        TDesc{ff_w2, En * En, Pn, En},
        TDesc{ff_w1, En * En, Pn, En},
        TDesc{ff_w1, En * En, Pn, En},
        TDesc{ff_w1, En * En, Pn, En},
        w_f1);

    // --- fused Wo projections + residual + double LN -> AO (b2) ---
    wo_ln_fused<<<dim3(32, 1, 24), 256, 0, stream>>>(
        b3, b4, w_os, w_ot, xb, ln_g, ln_b, b2);

    // --- fused FF (w1+relu+w2+biases) + residual + final LN -> out ---
    ff_ln_fused<<<dim3(32, 1, 24), 256, 0, stream>>>(
        b2, w_f1, w_f2, ff_b1, ff_b2, ln_g, ln_b, out);
}

// Round 6
// 386.338 us; speedup vs baseline: 1.0352x; 1.0025x over previous
//
#include <hip/hip_runtime.h>
#include <hip/hip_bf16.h>

constexpr int Bn = 16, Cn = 24, Sn = 128, En = 256, Hn = 8, Pn = 32;
constexpr size_t NBUF = (size_t)Bn * Cn * Sn * En;   // 12,582,912 elems
constexpr size_t WSLOT = (size_t)Cn * 256 * 256;     // 1,572,864

typedef __bf16 bf16_t;
typedef bf16_t bf16x8 __attribute__((ext_vector_type(8)));
typedef bf16_t bf16x4 __attribute__((ext_vector_type(4)));
typedef float f32x4 __attribute__((ext_vector_type(4)));

// global -> LDS direct 16B copy (dest = wave-uniform base + lane*16)
__device__ __forceinline__ void gl2lds16(const bf16_t* g, bf16_t* l) {
    typedef const __attribute__((address_space(1))) unsigned int* gp_t;
    typedef __attribute__((address_space(3))) unsigned int* lp_t;
    __builtin_amdgcn_global_load_lds((gp_t)(unsigned long long)g,
                                     (lp_t)(unsigned int)(unsigned long long)l,
                                     16, 0, 0);
}

// ---------------------------------------------------------------------------
// x fp32 -> bf16
// ---------------------------------------------------------------------------
__global__ __launch_bounds__(256) void conv_x_k(const float* __restrict__ x,
                                                bf16_t* __restrict__ xb) {
    const size_t i = ((size_t)blockIdx.x * 256 + threadIdx.x) * 4;
    const float4 v = *(const float4*)(x + i);
    bf16x4 o = {(bf16_t)v.x, (bf16_t)v.y, (bf16_t)v.z, (bf16_t)v.w};
    *(bf16x4*)(xb + i) = o;
}

// ---------------------------------------------------------------------------
// Wq_s copy-convert (source already e-contiguous): [h,c,p,e] -> [c][n=h*32+p][e]
// ---------------------------------------------------------------------------
__global__ __launch_bounds__(256) void conv_w_copy_k(const float* __restrict__ W,
                                                     bf16_t* __restrict__ out) {
    const int row = blockIdx.x * 4 + (threadIdx.x >> 6);   // c*256+n
    const int lane = threadIdx.x & 63;
    const int n = row & 255, c = row >> 8;
    const float* src = W + (size_t)c * (Pn * En) + (size_t)(n >> 5) * (Cn * Pn * En) +
                       (size_t)(n & 31) * En + lane * 4;
    const float4 v = *(const float4*)src;
    bf16x4 o = {(bf16_t)v.x, (bf16_t)v.y, (bf16_t)v.z, (bf16_t)v.w};
    *(bf16x4*)(out + (size_t)row * 256 + lane * 4) = o;
}

// ---------------------------------------------------------------------------
// Transpose-convert for e-strided weights -> canonical [slot][c][n][e].
// ---------------------------------------------------------------------------
struct TDesc { const float* W; int Sc, Snh, Se; };

__global__ __launch_bounds__(256) void conv_w_tr_k(
    TDesc d0, TDesc d1, TDesc d2, TDesc d3, TDesc d4,
    bf16_t* __restrict__ out)
{
    TDesc d;
    switch (blockIdx.z) {
        case 0: d = d0; break; case 1: d = d1; break; case 2: d = d2; break;
        case 3: d = d3; break; default: d = d4; break;
    }
    const int g = blockIdx.x & 7, et = blockIdx.x >> 3;
    const int c = blockIdx.y;

    __shared__ float tile[32][65];

    const int t = threadIdx.x;
    const float* base = d.W + (size_t)c * d.Sc + (size_t)g * d.Snh;

#pragma unroll
    for (int pass = 0; pass < 2; ++pass) {
        const int e_local = pass * 32 + (t >> 3);
        const int j4 = (t & 7) * 4;
        const float4 v = *(const float4*)(base + (size_t)(et * 64 + e_local) * d.Se + j4);
        tile[j4 + 0][e_local] = v.x;
        tile[j4 + 1][e_local] = v.y;
        tile[j4 + 2][e_local] = v.z;
        tile[j4 + 3][e_local] = v.w;
    }
    __syncthreads();

    const int j = t >> 3, e8 = (t & 7) * 8;
    bf16x8 o;
#pragma unroll
    for (int k = 0; k < 8; ++k) o[k] = (bf16_t)tile[j][e8 + k];
    *(bf16x8*)(out + (size_t)blockIdx.z * WSLOT +
               ((size_t)c * 256 + g * 32 + j) * 256 + et * 64 + e8) = o;
}

// small shared spatial k/v weights (tiny: 64 KB each)
__global__ __launch_bounds__(256) void conv_w_k(const float* __restrict__ W,
                                                bf16_t* __restrict__ Wb,
                                                int Sc, int Snh, int Snp, int Se) {
    const int n = blockIdx.x & 255, c = blockIdx.x >> 8;
    const int e = threadIdx.x;
    Wb[(size_t)blockIdx.x * 256 + e] =
        (bf16_t)W[(size_t)c * Sc + (size_t)(n >> 5) * Snh + (n & 31) * Snp + (size_t)e * Se];
}

// ---------------------------------------------------------------------------
// bf16 MFMA GEMM (QKV projections), 3 fused projections sharing A.
// 3-buf counted-vmcnt pipeline + source-side XOR swizzle (see R4 notes).
// trans=0: output n-inner; trans=1: output m-inner.
// ---------------------------------------------------------------------------
struct GDesc { const bf16_t* W; bf16_t* O; int Aoff, Wc, Ob, Oc, Os, Onh, Onp, trans; };

template <int NP>
__global__ __launch_bounds__(256) void gemm_mfma(
    const bf16_t* __restrict__ A, int Ab, int Ac, int As,
    GDesc g0, GDesc g1, GDesc g2)
{
    const int b = blockIdx.x, c = blockIdx.z;
    const int proj = (NP == 1) ? 0 : ((int)blockIdx.y >> 1);
    const int nt = (NP == 1) ? (int)blockIdx.y : ((int)blockIdx.y & 1);
    GDesc g = (proj == 0) ? g0 : (proj == 1) ? g1 : g2;

    __shared__ bf16_t smem[3][2][128 * 32];   // 48 KB
    bf16_t* Cs = &smem[0][0][0];              // epilogue staging (aliased)

    const int tid = threadIdx.x, wv = tid >> 6, ln = tid & 63;
    const int wm = (wv >> 1) * 64, wn = (wv & 1) * 64;
    const int lr = ln & 15, hi = ln >> 4;

    const bf16_t* Abase = A + g.Aoff + (size_t)b * Ab + (size_t)c * Ac;
    const bf16_t* Bbase = g.W + (size_t)c * g.Wc + (size_t)(nt * 128) * 256;

    auto stage = [&](int buf, int kt) {
        const int k0 = kt * 32;
#pragma unroll
        for (int it = 0; it < 2; ++it) {
            const int cb = it * 256 + wv * 64;
            const int mc = cb + ln;
            const int row = mc >> 2;
            const int kc = (((mc & 3) ^ ((row >> 1) & 3)) * 8);
            gl2lds16(Abase + (size_t)row * As + k0 + kc, &smem[buf][0][cb * 8]);
            gl2lds16(Bbase + (size_t)row * 256 + k0 + kc, &smem[buf][1][cb * 8]);
        }
    };

    f32x4 acc[4][4] = {};

    stage(0, 0);
    stage(1, 1);

#pragma unroll
    for (int kt = 0; kt < 8; ++kt) {
        if (kt < 6) stage((kt + 2) % 3, kt + 2);
        if (kt < 6)       asm volatile("s_waitcnt vmcnt(8)" ::: "memory");
        else if (kt == 6) asm volatile("s_waitcnt vmcnt(4)" ::: "memory");
        else              asm volatile("s_waitcnt vmcnt(0)" ::: "memory");
        __builtin_amdgcn_s_barrier();
        __builtin_amdgcn_sched_barrier(0);

        const int cur = kt % 3;
        bf16x8 af[4], bfr[4];
#pragma unroll
        for (int i = 0; i < 4; ++i) {
            const int r = wm + i * 16 + lr;
            af[i] = *(const bf16x8*)&smem[cur][0][r * 32 + ((hi ^ ((r >> 1) & 3)) * 8)];
        }
#pragma unroll
        for (int j = 0; j < 4; ++j) {
            const int r = wn + j * 16 + lr;
            bfr[j] = *(const bf16x8*)&smem[cur][1][r * 32 + ((hi ^ ((r >> 1) & 3)) * 8)];
        }
        __builtin_amdgcn_s_setprio(1);
#pragma unroll
        for (int i = 0; i < 4; ++i)
#pragma unroll
            for (int j = 0; j < 4; ++j)
                acc[i][j] = __builtin_amdgcn_mfma_f32_16x16x32_bf16(af[i], bfr[j], acc[i][j], 0, 0, 0);
        __builtin_amdgcn_s_setprio(0);

        __builtin_amdgcn_sched_barrier(0);
        __builtin_amdgcn_s_barrier();
    }

#pragma unroll
    for (int pass = 0; pass < 2; ++pass) {
        if (!g.trans) {
            if (wm == pass * 64) {
#pragma unroll
                for (int i = 0; i < 4; ++i)
#pragma unroll
                    for (int j = 0; j < 4; ++j)
#pragma unroll
                        for (int r = 0; r < 4; ++r)
                            Cs[(i * 16 + hi * 4 + r) * 136 + wn + j * 16 + lr] =
                                (bf16_t)acc[i][j][r];
            }
            __syncthreads();
#pragma unroll
            for (int it = 0; it < 2; ++it) {
                const int lrow = it * 32 + (tid >> 3);
                const int n0 = (tid & 7) * 16;
                bf16x8 v0 = *(const bf16x8*)&Cs[lrow * 136 + n0];
                bf16x8 v1 = *(const bf16x8*)&Cs[lrow * 136 + n0 + 8];
                const int m = pass * 64 + lrow;
                const int n = nt * 128 + n0;
                bf16_t* dst = g.O + (size_t)b * g.Ob + (size_t)c * g.Oc +
                              (size_t)m * g.Os + (size_t)(n >> 5) * g.Onh + (n & 31);
                *(bf16x8*)dst = v0;
                *(bf16x8*)(dst + 8) = v1;
            }
            __syncthreads();
        } else {
            if (wn == pass * 64) {
#pragma unroll
                for (int i = 0; i < 4; ++i)
#pragma unroll
                    for (int j = 0; j < 4; ++j) {
                        bf16x4 pk = {(bf16_t)acc[i][j][0], (bf16_t)acc[i][j][1],
                                     (bf16_t)acc[i][j][2], (bf16_t)acc[i][j][3]};
                        *(bf16x4*)&Cs[(j * 16 + lr) * 136 + wm + i * 16 + hi * 4] = pk;
                    }
            }
            __syncthreads();
#pragma unroll
            for (int it = 0; it < 2; ++it) {
                const int lrow = it * 32 + (tid >> 3);
                const int m0 = (tid & 7) * 16;
                bf16x8 v0 = *(const bf16x8*)&Cs[lrow * 136 + m0];
                bf16x8 v1 = *(const bf16x8*)&Cs[lrow * 136 + m0 + 8];
                const int n = nt * 128 + pass * 64 + lrow;
                bf16_t* dst = g.O + (size_t)b * g.Ob + (size_t)c * g.Oc +
                              (size_t)(n >> 5) * g.Onh + (size_t)(n & 31) * g.Onp + m0;
                *(bf16x8*)dst = v0;
                *(bf16x8*)(dst + 8) = v1;
            }
            __syncthreads();
        }
    }
}

// ---------------------------------------------------------------------------
// Fused: AO = LN(x + attnS*Wo_s) + LN(x + attnT*Wo_t)        [wo_ln_fused]
// Block = 64 rows x 256 cols; 4 waves = 4 n-slices; 16 K-steps (8 per branch).
// K-loop now 3-buf depth-2 counted-vmcnt (T3+T4, matching the QKV schedule):
// stage(t+2), s_waitcnt vmcnt(10) steady (2 tiles x 5 loads in flight),
// tail vmcnt(5)/vmcnt(0). Results staged to LDS; row-parallel LN pass.
// LDS: stage bufs 3 x 10240 elems [0,30720); Ss [0,16896), Ts [16896,33792)
// alias the dead stage area. 67.6 KB -> 2 blocks/CU.
// ---------------------------------------------------------------------------
__global__ __launch_bounds__(256) void wo_ln_fused(
    const bf16_t* __restrict__ A1, const bf16_t* __restrict__ A2,
    const bf16_t* __restrict__ W1, const bf16_t* __restrict__ W2,
    const bf16_t* __restrict__ xb, const float* __restrict__ g,
    const float* __restrict__ beta, bf16_t* __restrict__ AO)
{
    const int bx = blockIdx.x, c = blockIdx.z;
    const int R = ((bx >> 1) * Cn + c) * Sn + (bx & 1) * 64;

    __shared__ bf16_t lds[33792];

    const int tid = threadIdx.x, wv = tid >> 6, ln = tid & 63;
    const int wn = wv * 64, lr = ln & 15, hi = ln >> 4;

    const bf16_t* Ab0 = A1 + (size_t)R * 256;
    const bf16_t* Ab1 = A2 + (size_t)R * 256;
    const bf16_t* Wb0 = W1 + (size_t)c * 65536;
    const bf16_t* Wb1 = W2 + (size_t)c * 65536;

    auto stage = [&](int buf, int t) {
        const bf16_t* Asrc = (t < 8) ? Ab0 : Ab1;
        const bf16_t* Wsrc = (t < 8) ? Wb0 : Wb1;
        const int k0 = (t & 7) * 32;
        bf16_t* base = &lds[buf * 10240];
        {
            const int ch = wv * 64 + ln;            // A: 256 chunks
            const int row = ch >> 2;
            const int kc = (((ch & 3) ^ ((row >> 1) & 3)) * 8);
            gl2lds16(Asrc + (size_t)row * 256 + k0 + kc, base + ch * 8);
        }
#pragma unroll
        for (int g2 = 0; g2 < 4; ++g2) {            // B: 1024 chunks
            const int ch = g2 * 256 + wv * 64 + ln;
            const int row = ch >> 2;
            const int kc = (((ch & 3) ^ ((row >> 1) & 3)) * 8);
            gl2lds16(Wsrc + (size_t)row * 256 + k0 + kc, base + 2048 + ch * 8);
        }
    };

    f32x4 accS[4][4] = {}, accT[4][4] = {};

    stage(0, 0);               // 5 loads in flight
    stage(1, 1);               // 10
#pragma unroll
    for (int t = 0; t < 16; ++t) {
        if (t < 14) {
            stage((t + 2) % 3, t + 2);             // depth-2 prefetch
            asm volatile("s_waitcnt vmcnt(10)" ::: "memory");
        } else if (t == 14) {
            asm volatile("s_waitcnt vmcnt(5)" ::: "memory");
        } else {
            asm volatile("s_waitcnt vmcnt(0)" ::: "memory");
        }
        __builtin_amdgcn_s_barrier();
        __builtin_amdgcn_sched_barrier(0);

        const bf16_t* base = &lds[(t % 3) * 10240];
        bf16x8 af[4], bfr[4];
#pragma unroll
        for (int i = 0; i < 4; ++i) {
            const int r = i * 16 + lr;
            af[i] = *(const bf16x8*)(base + r * 32 + ((hi ^ ((r >> 1) & 3)) * 8));
        }
#pragma unroll
        for (int j = 0; j < 4; ++j) {
            const int r = wn + j * 16 + lr;
            bfr[j] = *(const bf16x8*)(base + 2048 + r * 32 + ((hi ^ ((r >> 1) & 3)) * 8));
        }
        __builtin_amdgcn_s_setprio(1);
        if (t < 8) {
#pragma unroll
            for (int i = 0; i < 4; ++i)
#pragma unroll
                for (int j = 0; j < 4; ++j)
                    accS[i][j] = __builtin_amdgcn_mfma_f32_16x16x32_bf16(af[i], bfr[j], accS[i][j], 0, 0, 0);
        } else {
#pragma unroll
            for (int i = 0; i < 4; ++i)
#pragma unroll
                for (int j = 0; j < 4; ++j)
                    accT[i][j] = __builtin_amdgcn_mfma_f32_16x16x32_bf16(af[i], bfr[j], accT[i][j], 0, 0, 0);
        }
        __builtin_amdgcn_s_setprio(0);
        __builtin_amdgcn_sched_barrier(0);
        __builtin_amdgcn_s_barrier();
    }

    // stage results (stage bufs dead)
    bf16_t* Ss = &lds[0];
    bf16_t* Ts = &lds[16896];
#pragma unroll
    for (int i = 0; i < 4; ++i)
#pragma unroll
        for (int j = 0; j < 4; ++j)
#pragma unroll
            for (int r = 0; r < 4; ++r) {
                const int m = i * 16 + hi * 4 + r;
                const int n = wn + j * 16 + lr;
                Ss[m * 264 + n] = (bf16_t)accS[i][j][r];
                Ts[m * 264 + n] = (bf16_t)accT[i][j][r];
            }
    __syncthreads();

    // row-parallel LN pass: 4 threads per row, 64 cols each
    const int row = tid >> 2, c0 = (tid & 3) * 64;
    const bf16_t* xp = xb + (size_t)(R + row) * 256 + c0;
    bf16x8 xv[8];
    float s1 = 0, q1 = 0, s2 = 0, q2 = 0;
#pragma unroll
    for (int u = 0; u < 8; ++u) {
        xv[u] = *(const bf16x8*)(xp + u * 8);
        bf16x8 sv = *(const bf16x8*)&Ss[row * 264 + c0 + u * 8];
        bf16x8 tv = *(const bf16x8*)&Ts[row * 264 + c0 + u * 8];
#pragma unroll
        for (int e = 0; e < 8; ++e) {
            const float xf = (float)xv[u][e];
            const float a = xf + (float)sv[e];
            const float t2 = xf + (float)tv[e];
            s1 += a; q1 += a * a; s2 += t2; q2 += t2 * t2;
        }
    }
    s1 += __shfl_xor(s1, 1); s1 += __shfl_xor(s1, 2);
    q1 += __shfl_xor(q1, 1); q1 += __shfl_xor(q1, 2);
    s2 += __shfl_xor(s2, 1); s2 += __shfl_xor(s2, 2);
    q2 += __shfl_xor(q2, 1); q2 += __shfl_xor(q2, 2);
    const float mu1 = s1 / 256.f, mu2 = s2 / 256.f;
    const float r1 = rsqrtf(q1 / 256.f - mu1 * mu1 + 1e-6f);
    const float r2 = rsqrtf(q2 / 256.f - mu2 * mu2 + 1e-6f);
#pragma unroll
    for (int u = 0; u < 8; ++u) {
        bf16x8 sv = *(const bf16x8*)&Ss[row * 264 + c0 + u * 8];
        bf16x8 tv = *(const bf16x8*)&Ts[row * 264 + c0 + u * 8];
        bf16x8 o8;
#pragma unroll
        for (int e = 0; e < 8; ++e) {
            const int n = c0 + u * 8 + e;
            const float xf = (float)xv[u][e];
            const float a = xf + (float)sv[e];
            const float t2 = xf + (float)tv[e];
            o8[e] = (bf16_t)((a - mu1) * r1 * g[n] + (t2 - mu2) * r2 * g[n] + 2.f * beta[n]);
        }
        *(bf16x8*)(AO + (size_t)(R + row) * 256 + c0 + u * 8) = o8;
    }
}

// ---------------------------------------------------------------------------
// Fused: out = LN(AO + (relu(AO*W1+b1))*W2+b2)               [ff_ln_fused]
// Loop1: A=AO (staged), W=W1 -> h = relu(.+b1) -> Hs LDS [64][264].
// Loop2: A-fragments read directly from Hs (no staging), W=W2 -> Fs (+b2).
// Row-parallel LN(AO+Fs) writes final f32 output.
// LDS: stage [0,20480); Hs [20480,37376); Fs aliases [0,16896). 74.8 KB.
// (3-buf upgrade would push LDS to 95 KB -> 1 block/CU; kept depth-1.)
// ---------------------------------------------------------------------------
__global__ __launch_bounds__(256) void ff_ln_fused(
    const bf16_t* __restrict__ AO, const bf16_t* __restrict__ W1,
    const bf16_t* __restrict__ W2, const float* __restrict__ b1v,
    const float* __restrict__ b2v, const float* __restrict__ g,
    const float* __restrict__ beta, float* __restrict__ out)
{
    const int bx = blockIdx.x, c = blockIdx.z;
    const int R = ((bx >> 1) * Cn + c) * Sn + (bx & 1) * 64;

    __shared__ bf16_t lds[37376];

    const int tid = threadIdx.x, wv = tid >> 6, ln = tid & 63;
    const int wn = wv * 64, lr = ln & 15, hi = ln >> 4;

    const bf16_t* Abase = AO + (size_t)R * 256;
    const bf16_t* W1b = W1 + (size_t)c * 65536;
    const bf16_t* W2b = W2 + (size_t)c * 65536;
    bf16_t* Hs = &lds[20480];

    auto stageA = [&](int buf, int kt) {
        const int k0 = kt * 32;
        const int ch = wv * 64 + ln;
        const int row = ch >> 2;
        const int kc = (((ch & 3) ^ ((row >> 1) & 3)) * 8);
        gl2lds16(Abase + (size_t)row * 256 + k0 + kc, &lds[buf * 10240] + ch * 8);
    };
    auto stageB = [&](int buf, int kt, const bf16_t* Wsrc) {
        const int k0 = kt * 32;
#pragma unroll
        for (int g2 = 0; g2 < 4; ++g2) {
            const int ch = g2 * 256 + wv * 64 + ln;
            const int row = ch >> 2;
            const int kc = (((ch & 3) ^ ((row >> 1) & 3)) * 8);
            gl2lds16(Wsrc + (size_t)row * 256 + k0 + kc, &lds[buf * 10240] + 2048 + ch * 8);
        }
    };

    f32x4 acc[4][4] = {};

    // ---- loop 1: h = AO * W1 ----
    stageA(0, 0); stageB(0, 0, W1b);
#pragma unroll
    for (int t = 0; t < 8; ++t) {
        if (t < 7) {
            stageA((t + 1) & 1, t + 1); stageB((t + 1) & 1, t + 1, W1b);
            asm volatile("s_waitcnt vmcnt(5)" ::: "memory");
        } else {
            asm volatile("s_waitcnt vmcnt(0)" ::: "memory");
        }
        __builtin_amdgcn_s_barrier();
        __builtin_amdgcn_sched_barrier(0);
        const bf16_t* base = &lds[(t & 1) * 10240];
        bf16x8 af[4], bfr[4];
#pragma unroll
        for (int i = 0; i < 4; ++i) {
            const int r = i * 16 + lr;
            af[i] = *(const bf16x8*)(base + r * 32 + ((hi ^ ((r >> 1) & 3)) * 8));
        }
#pragma unroll
        for (int j = 0; j < 4; ++j) {
            const int r = wn + j * 16 + lr;
            bfr[j] = *(const bf16x8*)(base + 2048 + r * 32 + ((hi ^ ((r >> 1) & 3)) * 8));
        }
        __builtin_amdgcn_s_setprio(1);
#pragma unroll
        for (int i = 0; i < 4; ++i)
#pragma unroll
            for (int j = 0; j < 4; ++j)
                acc[i][j] = __builtin_amdgcn_mfma_f32_16x16x32_bf16(af[i], bfr[j], acc[i][j], 0, 0, 0);
        __builtin_amdgcn_s_setprio(0);
        __builtin_amdgcn_sched_barrier(0);
        __builtin_amdgcn_s_barrier();
    }

    // interlude: issue first W2 tile, write h (bias+relu), sync
    stageB(0, 0, W2b);
#pragma unroll
    for (int i = 0; i < 4; ++i)
#pragma unroll
        for (int j = 0; j < 4; ++j) {
            const int n = wn + j * 16 + lr;
            const float bv = b1v[c * 256 + n];
#pragma unroll
            for (int r = 0; r < 4; ++r)
                Hs[(i * 16 + hi * 4 + r) * 264 + n] =
                    (bf16_t)fmaxf(acc[i][j][r] + bv, 0.f);
        }
    __syncthreads();

    // ---- loop 2: ff = h * W2 (A-fragments straight from Hs) ----
    f32x4 acc2[4][4] = {};
#pragma unroll
    for (int t = 0; t < 8; ++t) {
        if (t < 7) {
            stageB((t + 1) & 1, t + 1, W2b);
            asm volatile("s_waitcnt vmcnt(4)" ::: "memory");
        } else {
            asm volatile("s_waitcnt vmcnt(0)" ::: "memory");
        }
        __builtin_amdgcn_s_barrier();
        __builtin_amdgcn_sched_barrier(0);
        const bf16_t* base = &lds[(t & 1) * 10240];
        bf16x8 af[4], bfr[4];
#pragma unroll
        for (int i = 0; i < 4; ++i)
            af[i] = *(const bf16x8*)&Hs[(i * 16 + lr) * 264 + t * 32 + hi * 8];
#pragma unroll
        for (int j = 0; j < 4; ++j) {
            const int r = wn + j * 16 + lr;
            bfr[j] = *(const bf16x8*)(base + 2048 + r * 32 + ((hi ^ ((r >> 1) & 3)) * 8));
        }
        __builtin_amdgcn_s_setprio(1);
#pragma unroll
        for (int i = 0; i < 4; ++i)
#pragma unroll
            for (int j = 0; j < 4; ++j)
                acc2[i][j] = __builtin_amdgcn_mfma_f32_16x16x32_bf16(af[i], bfr[j], acc2[i][j], 0, 0, 0);
        __builtin_amdgcn_s_setprio(0);
        __builtin_amdgcn_sched_barrier(0);
        __builtin_amdgcn_s_barrier();
    }

    // stage ff (+bias2)
    bf16_t* Fs = &lds[0];
#pragma unroll
    for (int i = 0; i < 4; ++i)
#pragma unroll
        for (int j = 0; j < 4; ++j) {
            const int n = wn + j * 16 + lr;
            const float bv = b2v[c * 256 + n];
#pragma unroll
            for (int r = 0; r < 4; ++r)
                Fs[(i * 16 + hi * 4 + r) * 264 + n] = (bf16_t)(acc2[i][j][r] + bv);
        }
    __syncthreads();

    // row-parallel LN(AO + ff) -> f32 out
    const int row = tid >> 2, c0 = (tid & 3) * 64;
    const bf16_t* ap = AO + (size_t)(R + row) * 256 + c0;
    bf16x8 av[8];
    float s = 0, q = 0;
#pragma unroll
    for (int u = 0; u < 8; ++u) {
        av[u] = *(const bf16x8*)(ap + u * 8);
        bf16x8 fv = *(const bf16x8*)&Fs[row * 264 + c0 + u * 8];
#pragma unroll
        for (int e = 0; e < 8; ++e) {
            const float a = (float)av[u][e] + (float)fv[e];
            s += a; q += a * a;
        }
    }
    s += __shfl_xor(s, 1); s += __shfl_xor(s, 2);
    q += __shfl_xor(q, 1); q += __shfl_xor(q, 2);
    const float mu = s / 256.f;
    const float rin = rsqrtf(q / 256.f - mu * mu + 1e-6f);
#pragma unroll
    for (int u = 0; u < 8; ++u) {
        bf16x8 fv = *(const bf16x8*)&Fs[row * 264 + c0 + u * 8];
        float4 o0, o1;
#pragma unroll
        for (int e = 0; e < 8; ++e) {
            const int n = c0 + u * 8 + e;
            const float a = (float)av[u][e] + (float)fv[e];
            const float v = (a - mu) * rin * g[n] + beta[n];
            if (e < 4) (&o0.x)[e] = v; else (&o1.x)[e - 4] = v;
        }
        float* dst = out + (size_t)(R + row) * 256 + c0 + u * 8;
        *(float4*)dst = o0;
        *(float4*)(dst + 4) = o1;
    }
}

// ---------------------------------------------------------------------------
// Spatial attention, MFMA, one wave per (b,s,h). 24x24 padded to 32.
// ---------------------------------------------------------------------------
__global__ __launch_bounds__(256) void attn_spatial_mfma(
    const bf16_t* __restrict__ Q, const bf16_t* __restrict__ K,
    const bf16_t* __restrict__ V, bf16_t* __restrict__ O)
{
    __shared__ bf16_t Ps[4][32 * 40];
    __shared__ bf16_t Vt[4][32 * 40];

    const int tid = threadIdx.x, wv = tid >> 6, ln = tid & 63;
    const int lr = ln & 15, hi = ln >> 4, lk = hi * 8;

    const int bsh = blockIdx.x * 4 + wv;
    const int h = bsh & 7, s = (bsh >> 3) & 127, b = bsh >> 10;
    const size_t qb = (size_t)bsh * (Cn * Pn);

    {
        const int p = ln >> 1, c0 = 24 + (ln & 1) * 4;
        bf16x4 z = {};
        *(bf16x4*)&Vt[wv][p * 40 + c0] = z;
    }
#pragma unroll
    for (int it = 0; it < 2; ++it) {
        const int ch = it * 64 + ln;
        if (ch < 96) {
            const int cc = ch >> 2, p0 = (ch & 3) * 8;
            bf16x8 v = *(const bf16x8*)(V + qb + cc * 32 + p0);
#pragma unroll
            for (int j = 0; j < 8; ++j)
                Vt[wv][(p0 + j) * 40 + cc] = v[j];
        }
    }

    bf16x8 aq0 = *(const bf16x8*)(Q + qb + lr * 32 + lk);
    bf16x8 aq1 = *(const bf16x8*)(Q + qb + (16 + lr) * 32 + lk);
    bf16x8 bk0 = *(const bf16x8*)(K + qb + lr * 32 + lk);
    bf16x8 bk1 = *(const bf16x8*)(K + qb + (16 + lr) * 32 + lk);
    const f32x4 zz = {0.f, 0.f, 0.f, 0.f};
    f32x4 sc[2][2];
    sc[0][0] = __builtin_amdgcn_mfma_f32_16x16x32_bf16(aq0, bk0, zz, 0, 0, 0);
    sc[0][1] = __builtin_amdgcn_mfma_f32_16x16x32_bf16(aq0, bk1, zz, 0, 0, 0);
    sc[1][0] = __builtin_amdgcn_mfma_f32_16x16x32_bf16(aq1, bk0, zz, 0, 0, 0);
    sc[1][1] = __builtin_amdgcn_mfma_f32_16x16x32_bf16(aq1, bk1, zz, 0, 0, 0);

    const float scale = 0.17677669529663687f;
#pragma unroll
    for (int i = 0; i < 2; ++i) {
        float s0[4], s1[4], mx[4];
#pragma unroll
        for (int r = 0; r < 4; ++r) {
            s0[r] = sc[i][0][r] * scale;
            s1[r] = (lr >= 8) ? -3.0e38f : sc[i][1][r] * scale;
            mx[r] = fmaxf(s0[r], s1[r]);
        }
#pragma unroll
        for (int d = 1; d < 16; d <<= 1)
#pragma unroll
            for (int r = 0; r < 4; ++r) mx[r] = fmaxf(mx[r], __shfl_xor(mx[r], d));
        float e0[4], e1[4], sm[4];
#pragma unroll
        for (int r = 0; r < 4; ++r) {
            e0[r] = __expf(s0[r] - mx[r]);
            e1[r] = __expf(s1[r] - mx[r]);
            sm[r] = e0[r] + e1[r];
        }
#pragma unroll
        for (int d = 1; d < 16; d <<= 1)
#pragma unroll
            for (int r = 0; r < 4; ++r) sm[r] += __shfl_xor(sm[r], d);
#pragma unroll
        for (int r = 0; r < 4; ++r) {
            const float inv = 1.f / sm[r];
            const int row = i * 16 + hi * 4 + r;
            Ps[wv][row * 40 + lr]      = (bf16_t)(e0[r] * inv);
            Ps[wv][row * 40 + 16 + lr] = (bf16_t)(e1[r] * inv);
        }
    }

    bf16x8 ap0 = *(const bf16x8*)&Ps[wv][lr * 40 + lk];
    bf16x8 ap1 = *(const bf16x8*)&Ps[wv][(16 + lr) * 40 + lk];
    bf16x8 bv0 = *(const bf16x8*)&Vt[wv][lr * 40 + lk];
    bf16x8 bv1 = *(const bf16x8*)&Vt[wv][(16 + lr) * 40 + lk];
    f32x4 o[2][2];
    o[0][0] = __builtin_amdgcn_mfma_f32_16x16x32_bf16(ap0, bv0, zz, 0, 0, 0);
    o[0][1] = __builtin_amdgcn_mfma_f32_16x16x32_bf16(ap0, bv1, zz, 0, 0, 0);
    o[1][0] = __builtin_amdgcn_mfma_f32_16x16x32_bf16(ap1, bv0, zz, 0, 0, 0);
    o[1][1] = __builtin_amdgcn_mfma_f32_16x16x32_bf16(ap1, bv1, zz, 0, 0, 0);

#pragma unroll
    for (int i = 0; i < 2; ++i)
#pragma unroll
        for (int r = 0; r < 4; ++r) {
            const int c = i * 16 + hi * 4 + r;
            if (c < 24) {
                const size_t ob = ((size_t)(b * Cn + c) * Sn + s) * En + h * Pn;
#pragma unroll
                for (int j = 0; j < 2; ++j)
                    O[ob + j * 16 + lr] = (bf16_t)o[i][j][r];
            }
        }
}

// ---------------------------------------------------------------------------
// Temporal attention, MFMA. One block (4 waves) per (b,h,c).
// ---------------------------------------------------------------------------
__global__ __launch_bounds__(256) void attn_temporal_mfma(
    const bf16_t* __restrict__ Q, const bf16_t* __restrict__ K,
    const bf16_t* __restrict__ Vt, bf16_t* __restrict__ O)
{
    const int c = blockIdx.x, h = blockIdx.y, b = blockIdx.z;
    const size_t base = ((size_t)(b * Hn + h) * Cn + c) * (Sn * Pn);

    __shared__ bf16_t Qs[128 * 32];
    __shared__ bf16_t Ks[128 * 32];
    __shared__ bf16_t Vs[32 * 136];
    __shared__ bf16_t Ps[128 * 136];

    const int tid = threadIdx.x, wv = tid >> 6, ln = tid & 63;
    const int lr = ln & 15, lk = (ln >> 4) * 8;

#pragma unroll
    for (int it = 0; it < 2; ++it) {
        const int cb = it * 256 + wv * 64;
        const int mc = cb + ln;
        const int row = mc >> 2, kc = (mc & 3) * 8;
        gl2lds16(Q + base + row * 32 + kc, &Qs[cb * 8]);
        gl2lds16(K + base + row * 32 + kc, &Ks[cb * 8]);
    }
#pragma unroll
    for (int it = 0; it < 2; ++it) {
        const int mc = it * 256 + tid;
        const int p = mc >> 4, scn = (mc & 15) * 8;
        bf16x8 v = *(const bf16x8*)(Vt + base + p * 128 + scn);
        *(bf16x8*)&Vs[p * 136 + scn] = v;
    }
    __syncthreads();

    const int r0 = wv * 32;
    bf16x8 aq0 = *(const bf16x8*)&Qs[(r0 + lr) * 32 + lk];
    bf16x8 aq1 = *(const bf16x8*)&Qs[(r0 + 16 + lr) * 32 + lk];
    f32x4 sc_[2][8];
    const f32x4 zz = {0.f, 0.f, 0.f, 0.f};
#pragma unroll
    for (int j = 0; j < 8; ++j) {
        bf16x8 bk = *(const bf16x8*)&Ks[(j * 16 + lr) * 32 + lk];
        sc_[0][j] = __builtin_amdgcn_mfma_f32_16x16x32_bf16(aq0, bk, zz, 0, 0, 0);
        sc_[1][j] = __builtin_amdgcn_mfma_f32_16x16x32_bf16(aq1, bk, zz, 0, 0, 0);
    }

    const float scale = 0.17677669529663687f;
#pragma unroll
    for (int i = 0; i < 2; ++i) {
        float mx[4], sm[4];
#pragma unroll
        for (int r = 0; r < 4; ++r) {
            float m = sc_[i][0][r];
#pragma unroll
            for (int j = 1; j < 8; ++j) m = fmaxf(m, sc_[i][j][r]);
            mx[r] = m;
        }
#pragma unroll
        for (int d = 1; d < 16; d <<= 1)
#pragma unroll
            for (int r = 0; r < 4; ++r) mx[r] = fmaxf(mx[r], __shfl_xor(mx[r], d));
#pragma unroll
        for (int r = 0; r < 4; ++r) sm[r] = 0.f;
#pragma unroll
        for (int j = 0; j < 8; ++j)
#pragma unroll
            for (int r = 0; r < 4; ++r) {
                const float e = __expf((sc_[i][j][r] - mx[r]) * scale);
                sc_[i][j][r] = e; sm[r] += e;
            }
#pragma unroll
        for (int d = 1; d < 16; d <<= 1)
#pragma unroll
            for (int r = 0; r < 4; ++r) sm[r] += __shfl_xor(sm[r], d);
        float inv[4];
#pragma unroll
        for (int r = 0; r < 4; ++r) inv[r] = 1.f / sm[r];
        const int rb = r0 + i * 16 + (ln >> 4) * 4;
#pragma unroll
        for (int j = 0; j < 8; ++j)
#pragma unroll
            for (int r = 0; r < 4; ++r)
                Ps[(rb + r) * 136 + j * 16 + lr] = (bf16_t)(sc_[i][j][r] * inv[r]);
    }
    __syncthreads();

    f32x4 o[2][2] = {};
#pragma unroll
    for (int kk = 0; kk < 4; ++kk) {
        bf16x8 ap0 = *(const bf16x8*)&Ps[(r0 + lr) * 136 + kk * 32 + lk];
        bf16x8 ap1 = *(const bf16x8*)&Ps[(r0 + 16 + lr) * 136 + kk * 32 + lk];
        bf16x8 bv0 = *(const bf16x8*)&Vs[lr * 136 + kk * 32 + lk];
        bf16x8 bv1 = *(const bf16x8*)&Vs[(16 + lr) * 136 + kk * 32 + lk];
        o[0][0] = __builtin_amdgcn_mfma_f32_16x16x32_bf16(ap0, bv0, o[0][0], 0, 0, 0);
        o[0][1] = __builtin_amdgcn_mfma_f32_16x16x32_bf16(ap0, bv1, o[0][1], 0, 0, 0);
        o[1][0] = __builtin_amdgcn_mfma_f32_16x16x32_bf16(ap1, bv0, o[1][0], 0, 0, 0);
        o[1][1] = __builtin_amdgcn_mfma_f32_16x16x32_bf16(ap1, bv1, o[1][1], 0, 0, 0);
    }

#pragma unroll
    for (int i = 0; i < 2; ++i) {
        const int sb = r0 + i * 16 + (ln >> 4) * 4;
#pragma unroll
        for (int j = 0; j < 2; ++j) {
            const int p = h * 32 + j * 16 + lr;
#pragma unroll
            for (int r = 0; r < 4; ++r)
                O[((size_t)(b * Cn + c) * Sn + (sb + r)) * En + p] = (bf16_t)o[i][j][r];
        }
    }
}

// ---------------------------------------------------------------------------
extern "C" void kernel_launch(void* const* d_in, const int* in_sizes, int n_in,
                              void* d_out, int out_size, void* d_ws, size_t ws_size,
                              hipStream_t stream)
{
    const float* x     = (const float*)d_in[0];
    const float* Wq_s  = (const float*)d_in[1];
    const float* Wk_s  = (const float*)d_in[2];
    const float* Wv_s  = (const float*)d_in[3];
    const float* Wo_s  = (const float*)d_in[4];
    const float* Wq_t  = (const float*)d_in[5];
    const float* Wk_t  = (const float*)d_in[6];
    const float* Wv_t  = (const float*)d_in[7];
    const float* Wo_t  = (const float*)d_in[8];
    const float* ln_g  = (const float*)d_in[9];
    const float* ln_b  = (const float*)d_in[10];
    const float* ff_w1 = (const float*)d_in[11];
    const float* ff_b1 = (const float*)d_in[12];
    const float* ff_w2 = (const float*)d_in[13];
    const float* ff_b2 = (const float*)d_in[14];
    float* out = (float*)d_out;

    bf16_t* wsb = (bf16_t*)d_ws;
    bf16_t* b0 = wsb;
    bf16_t* b1 = wsb + NBUF;
    bf16_t* b2 = wsb + 2 * NBUF;
    bf16_t* b3 = wsb + 3 * NBUF;
    bf16_t* b4 = wsb + 4 * NBUF;

    // d_out doubles as scratch: xb + weight slots (consumed before out write)
    bf16_t* xb = (bf16_t*)d_out;
    bf16_t* wb = xb + NBUF;
    bf16_t* w_qs = wb + 0 * WSLOT;      // copy-convert slot
    bf16_t* wtr  = wb + 1 * WSLOT;      // 5 transpose slots
    bf16_t* w_os = wtr + 0 * WSLOT;
    bf16_t* w_qt = wtr + 1 * WSLOT;
    bf16_t* w_kt = wtr + 2 * WSLOT;
    bf16_t* w_vt = wtr + 3 * WSLOT;
    bf16_t* w_ot = wtr + 4 * WSLOT;
    bf16_t* w_ks = b4 + NBUF - 2 * 65536;   // consumed by spatial QKV before b4 written
    bf16_t* w_vs = b4 + NBUF - 65536;
    // ff weights converted LATE into b0 (free after attn_temporal reads Q);
    // needed because the f32 out write overlaps the d_out weight slots.
    bf16_t* w_f1 = b0;
    bf16_t* w_f2 = b0 + WSLOT;

    // strides
    const int XAb = Cn * Sn * En, XAc = Sn * En, XAs = En;                          // [B,C,S,E]
    const int QSb = Sn * Hn * Cn * Pn, QSs = Hn * Cn * Pn, QSh = Cn * Pn;           // [B,S,H,C,P]
    const int QTb = Hn * Cn * Sn * Pn, QTh = Cn * Sn * Pn, QTc = Sn * Pn, QTs = Pn; // [B,H,C,S,P]
    const int WCP = 256 * 256;

    // --- conversions (source-major, coalesced) ---
    conv_x_k<<<NBUF / 1024, 256, 0, stream>>>(x, xb);
    conv_w_copy_k<<<1536, 256, 0, stream>>>(Wq_s, w_qs);
    conv_w_tr_k<<<dim3(32, 24, 5), 256, 0, stream>>>(
        TDesc{Wo_s, En * En, Pn, En},                 // [c,e,f]: g=f>>5
        TDesc{Wq_t, En * Pn, Cn * En * Pn, Pn},       // [h,c,e,p]: g=h
        TDesc{Wk_t, En * Pn, Cn * En * Pn, Pn},
        TDesc{Wv_t, En * Pn, Cn * En * Pn, Pn},
        TDesc{Wo_t, En * En, Pn, En},
        wtr);
    conv_w_k<<<256, 256, 0, stream>>>(Wk_s, w_ks, 0, En * Pn, 1, Pn);
    conv_w_k<<<256, 256, 0, stream>>>(Wv_s, w_vs, 0, En * Pn, 1, Pn);

    // --- spatial branch QKV + attention -> b3 ---
    gemm_mfma<3><<<dim3(16, 6, 24), 256, 0, stream>>>(
        xb, XAb, XAc, XAs,
        GDesc{w_qs, b0, 0, WCP, QSb, Pn, QSs, QSh, 1, 0},
        GDesc{w_ks, b1, 0, 0,   QSb, Pn, QSs, QSh, 1, 0},
        GDesc{w_vs, b2, 0, 0,   QSb, Pn, QSs, QSh, 1, 0});
    attn_spatial_mfma<<<Bn * Sn * Hn / 4, 256, 0, stream>>>(b0, b1, b2, b3);

    // --- temporal branch QKV + attention -> b4 ---
    gemm_mfma<3><<<dim3(16, 6, 24), 256, 0, stream>>>(
        xb, XAb, XAc, XAs,
        GDesc{w_qt, b0, 0, WCP, QTb, QTc, QTs, QTh, 1, 0},
        GDesc{w_kt, b1, 0, WCP, QTb, QTc, QTs, QTh, 1, 0},
        GDesc{w_vt, b2, 0, WCP, QTb, QTc, 1, QTh, Sn, 1});
    attn_temporal_mfma<<<dim3(24, 8, 16), 256, 0, stream>>>(b0, b1, b2, b4);

    // --- late conversion of FF weights into b0 (b0 free after attn_temporal) ---
    conv_w_tr_k<<<dim3(32, 24, 2), 256, 0, stream>>>(
        TDesc{ff_w1, En * En, Pn, En},
        TDesc{ff_w2, En * En, Pn, En},
        TDesc{ff_w1, En * En, Pn, En},
        TDesc{ff_w1, En * En, Pn, En},
        TDesc{ff_w1, En * En, Pn, En},
        w_f1);

    // --- fused Wo projections + residual + double LN -> AO (b2) ---
    wo_ln_fused<<<dim3(32, 1, 24), 256, 0, stream>>>(
        b3, b4, w_os, w_ot, xb, ln_g, ln_b, b2);

    // --- fused FF (w1+relu+w2+biases) + residual + final LN -> out ---
    ff_ln_fused<<<dim3(32, 1, 24), 256, 0, stream>>>(
        b2, w_f1, w_f2, ff_b1, ff_b2, ln_g, ln_b, out);
}